// Round 1
// baseline (529.306 us; speedup 1.0000x reference)
//
#include <hip/hip_runtime.h>
#include <cstdint>

typedef __bf16 bf16_t;
typedef __attribute__((ext_vector_type(8))) __bf16 bf16x8;
typedef __attribute__((ext_vector_type(4))) float f32x4;

constexpr int Bx = 2, Nx = 2048, MEMx = 2048, Jx = 4096, DIMx = 1024, Hx = 16, HDx = 64;

__device__ __forceinline__ void gload_lds16(const bf16_t* g, bf16_t* lds) {
  __builtin_amdgcn_global_load_lds(
      (const __attribute__((address_space(1))) unsigned int*)g,
      (__attribute__((address_space(3))) unsigned int*)lds, 16, 0, 0);
}

// ---------------- convert / pack kernels ----------------
__global__ void k_build_bf16(const float* __restrict__ x, const float* __restrict__ mem,
                             bf16_t* __restrict__ xb, bf16_t* __restrict__ ctxb) {
  const int XT = Bx * Nx * DIMx;   // 4M
  const int CT = Bx * Jx * DIMx;   // 8M
  for (int i = blockIdx.x * blockDim.x + threadIdx.x; i < XT + CT;
       i += gridDim.x * blockDim.x) {
    if (i < XT) {
      xb[i] = (bf16_t)x[i];
    } else {
      int c = i - XT;
      int bb = c / (Jx * DIMx);
      int rr = c % (Jx * DIMx);
      int j = rr / DIMx, d = rr % DIMx;
      float v = (j < MEMx) ? mem[(int64_t)(bb * MEMx + j) * DIMx + d]
                           : x[(int64_t)(bb * Nx + (j - MEMx)) * DIMx + d];
      ctxb[c] = (bf16_t)v;
    }
  }
}

// WT[n*K + k] = W[k*Nc + n]
__global__ void k_transpose_w(const float* __restrict__ W, bf16_t* __restrict__ WT,
                              int K, int Nc) {
  int total = K * Nc;
  for (int i = blockIdx.x * blockDim.x + threadIdx.x; i < total;
       i += gridDim.x * blockDim.x) {
    int n = i / K, k = i % K;
    WT[i] = (bf16_t)W[(int64_t)k * Nc + n];
  }
}

// ---------------- GEMM: C[M,Nc] = A[M,K] @ BT[Nc,K]^T ----------------
template <int OUTF32>
__launch_bounds__(256)
__global__ void k_gemm_bt(const bf16_t* __restrict__ A, const bf16_t* __restrict__ BT,
                          void* __restrict__ Cv, const float* __restrict__ bias,
                          int M, int Nc, int K) {
  __shared__ bf16_t As[128 * 32];
  __shared__ bf16_t Bs[128 * 32];
  const int tid = threadIdx.x;
  const int w = tid >> 6, l = tid & 63;
  const int lr = l & 15, lg = l >> 4;
  const int m0 = blockIdx.y * 128, n0 = blockIdx.x * 128;
  const int wm = (w >> 1) * 64, wn = (w & 1) * 64;

  // staging: inst q in {0,1}: global row = q*64 + w*16 + (l>>2), col = (l&3)*8
  const int srow = w * 16 + (l >> 2);
  const int scol = (l & 3) * 8;
  const bf16_t* ga0 = A + (int64_t)(m0 + srow) * K + scol;
  const bf16_t* gb0 = BT + (int64_t)(n0 + srow) * K + scol;
  bf16_t* lA = As + w * 512;  // wave-uniform LDS base (HW adds lane*16B)
  bf16_t* lB = Bs + w * 512;

  f32x4 acc[4][4] = {};

  for (int k0 = 0; k0 < K; k0 += 32) {
    __syncthreads();
    gload_lds16(ga0 + k0, lA);
    gload_lds16(ga0 + (int64_t)64 * K + k0, lA + 2048);
    gload_lds16(gb0 + k0, lB);
    gload_lds16(gb0 + (int64_t)64 * K + k0, lB + 2048);
    __syncthreads();

    bf16x8 af[4], bfr[4];
#pragma unroll
    for (int t = 0; t < 4; ++t)
      af[t] = *(const bf16x8*)(As + (wm + t * 16 + lr) * 32 + lg * 8);
#pragma unroll
    for (int t = 0; t < 4; ++t)
      bfr[t] = *(const bf16x8*)(Bs + (wn + t * 16 + lr) * 32 + lg * 8);
#pragma unroll
    for (int mt = 0; mt < 4; ++mt)
#pragma unroll
      for (int nt = 0; nt < 4; ++nt)
        acc[mt][nt] = __builtin_amdgcn_mfma_f32_16x16x32_bf16(af[mt], bfr[nt],
                                                              acc[mt][nt], 0, 0, 0);
  }

#pragma unroll
  for (int mt = 0; mt < 4; ++mt) {
#pragma unroll
    for (int nt = 0; nt < 4; ++nt) {
      int col = n0 + wn + nt * 16 + lr;
#pragma unroll
      for (int r = 0; r < 4; ++r) {
        int row = m0 + wm + mt * 16 + lg * 4 + r;  // C/D: row=(lane>>4)*4+reg
        float v = acc[mt][nt][r];
        if constexpr (OUTF32) {
          ((float*)Cv)[(int64_t)row * Nc + col] = v + bias[col];
        } else {
          ((bf16_t*)Cv)[(int64_t)row * Nc + col] = (bf16_t)v;
        }
      }
    }
  }
}

// ---------------- flash attention ----------------
// grid: (N/128, H, B), 256 threads. Q-tile 128 rows (32/wave), KV-tile 64.
__launch_bounds__(256)
__global__ void k_attn(const bf16_t* __restrict__ Q, const bf16_t* __restrict__ KV,
                       const float* __restrict__ gate, bf16_t* __restrict__ Hout) {
  __shared__ bf16_t Ks[64 * 64];      // swizzled: phys = row*128B + ((chunk^(row&7))*16)
  __shared__ bf16_t Vs[64 * 80];      // V^T, pitch 160B, chunk ^= (d>>3)&7
  __shared__ bf16_t Ps[4][32 * 80];   // per-wave P, pitch 160B

  const int tid = threadIdx.x;
  const int w = tid >> 6, l = tid & 63;
  const int lr = l & 15, lg = l >> 4;
  const int b = blockIdx.z, h = blockIdx.y, q0 = blockIdx.x * 128;

  const bf16_t* Qb = Q + ((int64_t)b * Nx) * DIMx + h * HDx;
  const bf16_t* Kb = KV + ((int64_t)b * Jx) * (2 * DIMx) + h * HDx;
  const bf16_t* Vb = Kb + DIMx;
  const float* gb = gate + (int64_t)b * Jx;

  // Q fragments (A-operand: row = lane&15, k = (lane>>4)*8 + jj)
  bf16x8 qf[2][2];
#pragma unroll
  for (int mt = 0; mt < 2; ++mt)
#pragma unroll
    for (int kb = 0; kb < 2; ++kb)
      qf[mt][kb] = *(const bf16x8*)(Qb + (int64_t)(q0 + w * 32 + mt * 16 + lr) * DIMx +
                                    kb * 32 + lg * 8);

  f32x4 o[2][4] = {};
  float mrow[2][4], lrow[2][4];
#pragma unroll
  for (int mt = 0; mt < 2; ++mt)
#pragma unroll
    for (int r = 0; r < 4; ++r) { mrow[mt][r] = -1e30f; lrow[mt][r] = 0.f; }

  // K staging geometry: inst (w,q): rows (w*2+q)*8 + (l>>3), swizzled col
  const int ksrow = w * 16 + (l >> 3);           // q=0 rows; q=1 adds 8
  const int kscol = ((l & 7) ^ (l >> 3)) * 8;    // pre-swizzled global source col
  const int jend = (Jx < q0 + 127 + MEMx + 1) ? Jx : (q0 + 127 + MEMx + 1);
  const float LOG2E = 1.44269504088896f;
  const f32x4 zf = {0.f, 0.f, 0.f, 0.f};

  for (int j0 = 0; j0 < jend; j0 += 64) {
    __syncthreads();
    // stage K (global_load_lds, linear LDS dest + inverse-swizzled source)
    gload_lds16(Kb + (int64_t)(j0 + ksrow) * 2048 + kscol, Ks + w * 1024);
    gload_lds16(Kb + (int64_t)(j0 + ksrow + 8) * 2048 + kscol, Ks + w * 1024 + 512);
    // stage V transposed (reg-staged, swizzled writes: conflict-free)
#pragma unroll
    for (int t = 0; t < 2; ++t) {
      int vj = t * 32 + w * 8 + (l >> 3);
      int vd0 = (l & 7) * 8;
      bf16x8 vv = *(const bf16x8*)(Vb + (int64_t)(j0 + vj) * 2048 + vd0);
      int chx = ((t * 4 + w) ^ (l & 7)) * 16;  // (j>>3) ^ (d>>3)
#pragma unroll
      for (int i = 0; i < 8; ++i) {
        int d = vd0 + i;
        *(bf16_t*)((char*)Vs + d * 160 + chx + (l >> 3) * 2) = vv[i];
      }
    }
    __syncthreads();

    // K fragments (B-operand: col j = lane&15, k = d), swizzled read
    bf16x8 kf[4][2];
#pragma unroll
    for (int jt = 0; jt < 4; ++jt)
#pragma unroll
      for (int kb = 0; kb < 2; ++kb)
        kf[jt][kb] = *(const bf16x8*)((char*)Ks + (jt * 16 + lr) * 128 +
                                      (((kb * 4 + lg) ^ (lr & 7)) * 16));

    // S = (Q K^T) * scale
    f32x4 s[2][4];
#pragma unroll
    for (int mt = 0; mt < 2; ++mt)
#pragma unroll
      for (int jt = 0; jt < 4; ++jt) {
        f32x4 t0 = __builtin_amdgcn_mfma_f32_16x16x32_bf16(qf[mt][0], kf[jt][0], zf, 0, 0, 0);
        s[mt][jt] = __builtin_amdgcn_mfma_f32_16x16x32_bf16(qf[mt][1], kf[jt][1], t0, 0, 0, 0);
      }

    const bool need_mask = (j0 + 63 > q0 + MEMx);
#pragma unroll
    for (int mt = 0; mt < 2; ++mt)
#pragma unroll
      for (int jt = 0; jt < 4; ++jt)
#pragma unroll
        for (int r = 0; r < 4; ++r) {
          float v = s[mt][jt][r] * 0.125f;
          if (need_mask) {
            int i = q0 + w * 32 + mt * 16 + lg * 4 + r;
            int j = j0 + jt * 16 + lr;
            if (j > i + MEMx) v = -1e30f;
          }
          s[mt][jt][r] = v;
        }

    // online softmax (l accumulates UNGATED p; gating applied after, before PV)
#pragma unroll
    for (int mt = 0; mt < 2; ++mt) {
      float tm[4];
#pragma unroll
      for (int r = 0; r < 4; ++r)
        tm[r] = fmaxf(fmaxf(s[mt][0][r], s[mt][1][r]), fmaxf(s[mt][2][r], s[mt][3][r]));
#pragma unroll
      for (int off = 1; off < 16; off <<= 1)
#pragma unroll
        for (int r = 0; r < 4; ++r)
          tm[r] = fmaxf(tm[r], __shfl_xor(tm[r], off, 16));
      float al[4];
#pragma unroll
      for (int r = 0; r < 4; ++r) {
        float mnew = fmaxf(mrow[mt][r], tm[r]);
        al[r] = exp2f((mrow[mt][r] - mnew) * LOG2E);
        mrow[mt][r] = mnew;
        lrow[mt][r] *= al[r];
      }
#pragma unroll
      for (int nt = 0; nt < 4; ++nt)
#pragma unroll
        for (int r = 0; r < 4; ++r) o[mt][nt][r] *= al[r];
      float ps[4] = {0.f, 0.f, 0.f, 0.f};
#pragma unroll
      for (int jt = 0; jt < 4; ++jt)
#pragma unroll
        for (int r = 0; r < 4; ++r) {
          float p = exp2f((s[mt][jt][r] - mrow[mt][r]) * LOG2E);
          s[mt][jt][r] = p;
          ps[r] += p;
        }
#pragma unroll
      for (int off = 1; off < 16; off <<= 1)
#pragma unroll
        for (int r = 0; r < 4; ++r) ps[r] += __shfl_xor(ps[r], off, 16);
#pragma unroll
      for (int r = 0; r < 4; ++r) lrow[mt][r] += ps[r];
    }

    // gate + write P (bf16) to per-wave LDS
    float gv[4];
#pragma unroll
    for (int jt = 0; jt < 4; ++jt) gv[jt] = gb[j0 + jt * 16 + lr];
#pragma unroll
    for (int mt = 0; mt < 2; ++mt)
#pragma unroll
      for (int jt = 0; jt < 4; ++jt)
#pragma unroll
        for (int r = 0; r < 4; ++r)
          Ps[w][(mt * 16 + lg * 4 + r) * 80 + jt * 16 + lr] =
              (bf16_t)(s[mt][jt][r] * gv[jt]);

    __syncthreads();

    // PV
    bf16x8 vf[4][2], pf[2][2];
#pragma unroll
    for (int nt = 0; nt < 4; ++nt)
#pragma unroll
      for (int kb = 0; kb < 2; ++kb) {
        int d = nt * 16 + lr;
        vf[nt][kb] = *(const bf16x8*)((char*)Vs + d * 160 +
                                      (((kb * 4 + lg) ^ ((d >> 3) & 7)) * 16));
      }
#pragma unroll
    for (int mt = 0; mt < 2; ++mt)
#pragma unroll
      for (int kb = 0; kb < 2; ++kb)
        pf[mt][kb] = *(const bf16x8*)(Ps[w] + (mt * 16 + lr) * 80 + kb * 32 + lg * 8);
#pragma unroll
    for (int mt = 0; mt < 2; ++mt)
#pragma unroll
      for (int nt = 0; nt < 4; ++nt) {
        o[mt][nt] = __builtin_amdgcn_mfma_f32_16x16x32_bf16(pf[mt][0], vf[nt][0],
                                                            o[mt][nt], 0, 0, 0);
        o[mt][nt] = __builtin_amdgcn_mfma_f32_16x16x32_bf16(pf[mt][1], vf[nt][1],
                                                            o[mt][nt], 0, 0, 0);
      }
  }

  // epilogue: O /= l, store bf16
#pragma unroll
  for (int mt = 0; mt < 2; ++mt)
#pragma unroll
    for (int nt = 0; nt < 4; ++nt)
#pragma unroll
      for (int r = 0; r < 4; ++r) {
        int qrow = q0 + w * 32 + mt * 16 + lg * 4 + r;
        float v = o[mt][nt][r] / lrow[mt][r];
        Hout[(int64_t)(b * Nx + qrow) * DIMx + h * HDx + nt * 16 + lr] = (bf16_t)v;
      }
}

// ---------------- launcher ----------------
extern "C" void kernel_launch(void* const* d_in, const int* in_sizes, int n_in,
                              void* d_out, int out_size, void* d_ws, size_t ws_size,
                              hipStream_t stream) {
  const float* x    = (const float*)d_in[0];
  const float* mem  = (const float*)d_in[1];
  const float* expm = (const float*)d_in[2];
  const float* Wq   = (const float*)d_in[3];
  const float* Wkv  = (const float*)d_in[4];
  const float* Wo   = (const float*)d_in[5];
  const float* bo   = (const float*)d_in[6];
  float* out = (float*)d_out;

  bf16_t* p = (bf16_t*)d_ws;
  bf16_t* xb   = p; p += (size_t)Bx * Nx * DIMx;        // 4M
  bf16_t* ctxb = p; p += (size_t)Bx * Jx * DIMx;        // 8M
  bf16_t* WqT  = p; p += (size_t)DIMx * DIMx;           // 1M
  bf16_t* WkvT = p; p += (size_t)DIMx * 2 * DIMx;       // 2M
  bf16_t* WoT  = p; p += (size_t)DIMx * DIMx;           // 1M
  bf16_t* Qb   = p; p += (size_t)Bx * Nx * DIMx;        // 4M
  bf16_t* KVb  = p; p += (size_t)Bx * Jx * 2 * DIMx;    // 16M
  bf16_t* Ho   = p; p += (size_t)Bx * Nx * DIMx;        // 4M  (total 40M bf16 = 80MB)

  k_build_bf16<<<4096, 256, 0, stream>>>(x, mem, xb, ctxb);
  k_transpose_w<<<1024, 256, 0, stream>>>(Wq, WqT, DIMx, DIMx);
  k_transpose_w<<<2048, 256, 0, stream>>>(Wkv, WkvT, DIMx, 2 * DIMx);
  k_transpose_w<<<1024, 256, 0, stream>>>(Wo, WoT, DIMx, DIMx);

  k_gemm_bt<0><<<dim3(1024 / 128, 4096 / 128), 256, 0, stream>>>(
      xb, WqT, Qb, nullptr, Bx * Nx, DIMx, DIMx);
  k_gemm_bt<0><<<dim3(2048 / 128, 8192 / 128), 256, 0, stream>>>(
      ctxb, WkvT, KVb, nullptr, Bx * Jx, 2 * DIMx, DIMx);
  k_attn<<<dim3(Nx / 128, Hx, Bx), 256, 0, stream>>>(Qb, KVb, expm, Ho);
  k_gemm_bt<1><<<dim3(1024 / 128, 4096 / 128), 256, 0, stream>>>(
      Ho, WoT, out, bo, Bx * Nx, DIMx, DIMx);
}

// Round 3
// 349.362 us; speedup vs baseline: 1.5151x; 1.5151x over previous
//
#include <hip/hip_runtime.h>
#include <cstdint>

typedef __bf16 bf16_t;
typedef __attribute__((ext_vector_type(4))) __bf16 bf16x4;
typedef __attribute__((ext_vector_type(8))) __bf16 bf16x8;
typedef __attribute__((ext_vector_type(4))) float f32x4;
typedef __attribute__((ext_vector_type(4))) short s16x4;

constexpr int Bx = 2, Nx = 2048, MEMx = 2048, Jx = 4096, DIMx = 1024, Hx = 16, HDx = 64;

__device__ __forceinline__ void gload_lds16(const bf16_t* g, bf16_t* lds) {
  __builtin_amdgcn_global_load_lds(
      (const __attribute__((address_space(1))) unsigned int*)g,
      (__attribute__((address_space(3))) unsigned int*)lds, 16, 0, 0);
}

__device__ __forceinline__ f32x4 mfma16(bf16x4 a, bf16x4 b, f32x4 c) {
#if __has_builtin(__builtin_amdgcn_mfma_f32_16x16x16bf16_1k)
  return __builtin_amdgcn_mfma_f32_16x16x16bf16_1k(
      __builtin_bit_cast(s16x4, a), __builtin_bit_cast(s16x4, b), c, 0, 0, 0);
#else
  asm volatile("v_mfma_f32_16x16x16_bf16 %0, %1, %2, %0" : "+v"(c) : "v"(a), "v"(b));
  return c;
#endif
}

// ---------------- convert / pack kernels ----------------
__global__ void k_build_bf16(const float* __restrict__ x, const float* __restrict__ mem,
                             bf16_t* __restrict__ xb, bf16_t* __restrict__ ctxb) {
  const int XT = Bx * Nx * DIMx;
  const int CT = Bx * Jx * DIMx;
  for (int i = blockIdx.x * blockDim.x + threadIdx.x; i < XT + CT;
       i += gridDim.x * blockDim.x) {
    if (i < XT) {
      xb[i] = (bf16_t)x[i];
    } else {
      int c = i - XT;
      int bb = c / (Jx * DIMx);
      int rr = c % (Jx * DIMx);
      int j = rr / DIMx, d = rr % DIMx;
      float v = (j < MEMx) ? mem[(int64_t)(bb * MEMx + j) * DIMx + d]
                           : x[(int64_t)(bb * Nx + (j - MEMx)) * DIMx + d];
      ctxb[c] = (bf16_t)v;
    }
  }
}

__global__ void k_transpose_w(const float* __restrict__ W, bf16_t* __restrict__ WT,
                              int K, int Nc) {
  int total = K * Nc;
  for (int i = blockIdx.x * blockDim.x + threadIdx.x; i < total;
       i += gridDim.x * blockDim.x) {
    int n = i / K, k = i % K;
    WT[i] = (bf16_t)W[(int64_t)k * Nc + n];
  }
}

// ---------------- GEMM: C[M,Nc] = A[M,K] @ BT[Nc,K]^T ----------------
template <int OUTF32>
__launch_bounds__(256)
__global__ void k_gemm_bt(const bf16_t* __restrict__ A, const bf16_t* __restrict__ BT,
                          void* __restrict__ Cv, const float* __restrict__ bias,
                          int M, int Nc, int K) {
  __shared__ bf16_t As[128 * 32];
  __shared__ bf16_t Bs[128 * 32];
  const int tid = threadIdx.x;
  const int w = tid >> 6, l = tid & 63;
  const int lr = l & 15, lg = l >> 4;
  const int m0 = blockIdx.y * 128, n0 = blockIdx.x * 128;
  const int wm = (w >> 1) * 64, wn = (w & 1) * 64;

  const int srow = w * 16 + (l >> 2);
  const int scol = (l & 3) * 8;
  const bf16_t* ga0 = A + (int64_t)(m0 + srow) * K + scol;
  const bf16_t* gb0 = BT + (int64_t)(n0 + srow) * K + scol;
  bf16_t* lA = As + w * 512;
  bf16_t* lB = Bs + w * 512;

  f32x4 acc[4][4] = {};

  for (int k0 = 0; k0 < K; k0 += 32) {
    __syncthreads();
    gload_lds16(ga0 + k0, lA);
    gload_lds16(ga0 + (int64_t)64 * K + k0, lA + 2048);
    gload_lds16(gb0 + k0, lB);
    gload_lds16(gb0 + (int64_t)64 * K + k0, lB + 2048);
    __syncthreads();

    bf16x8 af[4], bfr[4];
#pragma unroll
    for (int t = 0; t < 4; ++t)
      af[t] = *(const bf16x8*)(As + (wm + t * 16 + lr) * 32 + lg * 8);
#pragma unroll
    for (int t = 0; t < 4; ++t)
      bfr[t] = *(const bf16x8*)(Bs + (wn + t * 16 + lr) * 32 + lg * 8);
#pragma unroll
    for (int mt = 0; mt < 4; ++mt)
#pragma unroll
      for (int nt = 0; nt < 4; ++nt)
        acc[mt][nt] = __builtin_amdgcn_mfma_f32_16x16x32_bf16(af[mt], bfr[nt],
                                                              acc[mt][nt], 0, 0, 0);
  }

#pragma unroll
  for (int mt = 0; mt < 4; ++mt) {
#pragma unroll
    for (int nt = 0; nt < 4; ++nt) {
      int col = n0 + wn + nt * 16 + lr;
#pragma unroll
      for (int r = 0; r < 4; ++r) {
        int row = m0 + wm + mt * 16 + lg * 4 + r;
        float v = acc[mt][nt][r];
        if constexpr (OUTF32) {
          ((float*)Cv)[(int64_t)row * Nc + col] = v + bias[col];
        } else {
          ((bf16_t*)Cv)[(int64_t)row * Nc + col] = (bf16_t)v;
        }
      }
    }
  }
}

// ---------------- flash attention (swapped QK^T, in-register softmax) ----------
// grid: (N/64, H, B), 256 threads (4 waves x 16 q-rows). KV-tile 64.
// S^T = mfma32(K, Q):  q = lane&15 (lane-local), j = jt*16 + lg*4 + r.
// PV:  O^T += mfma16(V^T, P^T) — P stays in registers (bf16x4 per jt).
__launch_bounds__(256)
__global__ void k_attn(const bf16_t* __restrict__ Q, const bf16_t* __restrict__ KV,
                       const float* __restrict__ gate, bf16_t* __restrict__ Hout) {
  __shared__ bf16_t Ks[64 * 64];   // swizzled: byte = row*128 + ((oct ^ (row&7))*16)
  __shared__ bf16_t Vs[64 * 80];   // V^T (gated), pitch 160B, chunk ^= (d>>3)&7

  const int tid = threadIdx.x;
  const int w = tid >> 6, l = tid & 63;
  const int lr = l & 15, lg = l >> 4;
  const int b = blockIdx.z, h = blockIdx.y, q0 = blockIdx.x * 64;

  const bf16_t* Qb = Q + ((int64_t)b * Nx) * DIMx + h * HDx;
  const bf16_t* Kb = KV + ((int64_t)b * Jx) * (2 * DIMx) + h * HDx;
  const bf16_t* Vb = Kb + DIMx;
  const float* gb = gate + (int64_t)b * Jx;

  const int qrow = q0 + w * 16 + lr;   // this lane's q (S^T column)

  // Q fragment as B-operand: col=q=lane&15, k(d) = kb*32 + lg*8 + jj
  bf16x8 qf[2];
#pragma unroll
  for (int kb = 0; kb < 2; ++kb)
    qf[kb] = *(const bf16x8*)(Qb + (int64_t)qrow * DIMx + kb * 32 + lg * 8);

  f32x4 o[4] = {};                 // O^T: d = nt*16 + lg*4 + r, q = lr
  float mrun = -1e30f, lsum = 0.f;

  const int ksrow = w * 16 + (l >> 3);
  const int kscol = ((l & 7) ^ (l >> 3)) * 8;   // inverse-swizzled global source
  const int jend = (Jx < q0 + 64 + MEMx) ? Jx : (q0 + 64 + MEMx);
  const float C2 = 0.125f * 1.44269504088896f;  // scale * log2(e)
  const f32x4 zf = {0.f, 0.f, 0.f, 0.f};

  for (int j0 = 0; j0 < jend; j0 += 64) {
    __syncthreads();
    // stage K via global_load_lds (linear dest + pre-swizzled source)
    gload_lds16(Kb + (int64_t)(j0 + ksrow) * 2048 + kscol, Ks + w * 1024);
    gload_lds16(Kb + (int64_t)(j0 + ksrow + 8) * 2048 + kscol, Ks + w * 1024 + 512);
    // stage V^T with expire-gate folded in (l must stay ungated; o gets gated V)
#pragma unroll
    for (int t = 0; t < 2; ++t) {
      int vj = t * 32 + w * 8 + (l >> 3);
      int vd0 = (l & 7) * 8;
      bf16x8 vv = *(const bf16x8*)(Vb + (int64_t)(j0 + vj) * 2048 + vd0);
      float g = gb[j0 + vj];
      int chx = ((t * 4 + w) ^ (l & 7)) * 16;  // (j>>3) ^ (d>>3)
#pragma unroll
      for (int i = 0; i < 8; ++i)
        *(bf16_t*)((char*)Vs + (vd0 + i) * 160 + chx + (l >> 3) * 2) =
            (bf16_t)(g * (float)vv[i]);
    }
    __syncthreads();

    // S^T = K · Q^T   (A = K-tile: row=j=lane&15, k=d; B = Q^T)
    f32x4 s[4];
#pragma unroll
    for (int jt = 0; jt < 4; ++jt) {
      bf16x8 kf0 = *(const bf16x8*)((char*)Ks + (jt * 16 + lr) * 128 +
                                    ((lg ^ (lr & 7)) * 16));
      bf16x8 kf1 = *(const bf16x8*)((char*)Ks + (jt * 16 + lr) * 128 +
                                    (((4 + lg) ^ (lr & 7)) * 16));
      f32x4 t0 = __builtin_amdgcn_mfma_f32_16x16x32_bf16(kf0, qf[0], zf, 0, 0, 0);
      s[jt] = __builtin_amdgcn_mfma_f32_16x16x32_bf16(kf1, qf[1], t0, 0, 0, 0);
    }

    // scale (in log2 units) + causal mask
    const bool need_mask = (j0 + 63 > q0 + MEMx);
#pragma unroll
    for (int jt = 0; jt < 4; ++jt)
#pragma unroll
      for (int r = 0; r < 4; ++r) {
        float v = s[jt][r] * C2;
        if (need_mask) {
          int j = j0 + jt * 16 + lg * 4 + r;
          if (j > qrow + MEMx) v = -1e30f;
        }
        s[jt][r] = v;
      }

    // online softmax — q is lane-local: 15 in-lane ops + 2 shfl_xor
    float tm = s[0][0];
#pragma unroll
    for (int jt = 0; jt < 4; ++jt)
#pragma unroll
      for (int r = 0; r < 4; ++r) tm = fmaxf(tm, s[jt][r]);
    tm = fmaxf(tm, __shfl_xor(tm, 16));
    tm = fmaxf(tm, __shfl_xor(tm, 32));

    float mnew = fmaxf(mrun, tm);
    float al = exp2f(mrun - mnew);
    mrun = mnew;

    float ps = 0.f;
#pragma unroll
    for (int jt = 0; jt < 4; ++jt)
#pragma unroll
      for (int r = 0; r < 4; ++r) {
        float p = exp2f(s[jt][r] - mnew);
        s[jt][r] = p;
        ps += p;
      }
    ps += __shfl_xor(ps, 16);
    ps += __shfl_xor(ps, 32);
    lsum = lsum * al + ps;
#pragma unroll
    for (int nt = 0; nt < 4; ++nt)
#pragma unroll
      for (int r = 0; r < 4; ++r) o[nt][r] *= al;

    // P^T fragments: k-layout of mfma16 B-operand == S^T D-layout (no lane moves)
    bf16x4 pf[4];
#pragma unroll
    for (int jt = 0; jt < 4; ++jt)
#pragma unroll
      for (int r = 0; r < 4; ++r) pf[jt][r] = (bf16_t)s[jt][r];

    // O^T += V^T · P^T  (A = V^T: row=d=lane&15, k=j = jt*16 + lg*4 + jj)
#pragma unroll
    for (int nt = 0; nt < 4; ++nt) {
      int d = nt * 16 + lr;
#pragma unroll
      for (int jt = 0; jt < 4; ++jt) {
        bf16x4 vf = *(const bf16x4*)((char*)Vs + d * 160 +
                                     (((jt * 2 + (lg >> 1)) ^ ((d >> 3) & 7)) * 16) +
                                     (lg & 1) * 8);
        o[nt] = mfma16(vf, pf[jt], o[nt]);
      }
    }
  }

  // epilogue: O^T / l, store (q = lr lane-local; d = nt*16 + lg*4 + r)
  float inv = 1.f / lsum;
#pragma unroll
  for (int nt = 0; nt < 4; ++nt) {
    bf16x4 ov;
#pragma unroll
    for (int r = 0; r < 4; ++r) ov[r] = (bf16_t)(o[nt][r] * inv);
    *(bf16x4*)(Hout + (int64_t)(b * Nx + qrow) * DIMx + h * HDx + nt * 16 + lg * 4) = ov;
  }
}

// ---------------- launcher ----------------
extern "C" void kernel_launch(void* const* d_in, const int* in_sizes, int n_in,
                              void* d_out, int out_size, void* d_ws, size_t ws_size,
                              hipStream_t stream) {
  const float* x    = (const float*)d_in[0];
  const float* mem  = (const float*)d_in[1];
  const float* expm = (const float*)d_in[2];
  const float* Wq   = (const float*)d_in[3];
  const float* Wkv  = (const float*)d_in[4];
  const float* Wo   = (const float*)d_in[5];
  const float* bo   = (const float*)d_in[6];
  float* out = (float*)d_out;

  bf16_t* p = (bf16_t*)d_ws;
  bf16_t* xb   = p; p += (size_t)Bx * Nx * DIMx;
  bf16_t* ctxb = p; p += (size_t)Bx * Jx * DIMx;
  bf16_t* WqT  = p; p += (size_t)DIMx * DIMx;
  bf16_t* WkvT = p; p += (size_t)DIMx * 2 * DIMx;
  bf16_t* WoT  = p; p += (size_t)DIMx * DIMx;
  bf16_t* Qb   = p; p += (size_t)Bx * Nx * DIMx;
  bf16_t* KVb  = p; p += (size_t)Bx * Jx * 2 * DIMx;
  bf16_t* Ho   = p; p += (size_t)Bx * Nx * DIMx;

  k_build_bf16<<<4096, 256, 0, stream>>>(x, mem, xb, ctxb);
  k_transpose_w<<<1024, 256, 0, stream>>>(Wq, WqT, DIMx, DIMx);
  k_transpose_w<<<2048, 256, 0, stream>>>(Wkv, WkvT, DIMx, 2 * DIMx);
  k_transpose_w<<<1024, 256, 0, stream>>>(Wo, WoT, DIMx, DIMx);

  k_gemm_bt<0><<<dim3(1024 / 128, 4096 / 128), 256, 0, stream>>>(
      xb, WqT, Qb, nullptr, Bx * Nx, DIMx, DIMx);
  k_gemm_bt<0><<<dim3(2048 / 128, 8192 / 128), 256, 0, stream>>>(
      ctxb, WkvT, KVb, nullptr, Bx * Jx, 2 * DIMx, DIMx);
  k_attn<<<dim3(Nx / 64, Hx, Bx), 256, 0, stream>>>(Qb, KVb, expm, Ho);
  k_gemm_bt<1><<<dim3(1024 / 128, 4096 / 128), 256, 0, stream>>>(
      Ho, WoT, out, bo, Bx * Nx, DIMx, DIMx);
}

// Round 4
// 324.786 us; speedup vs baseline: 1.6297x; 1.0757x over previous
//
#include <hip/hip_runtime.h>
#include <cstdint>

typedef __bf16 bf16_t;
typedef __attribute__((ext_vector_type(4))) __bf16 bf16x4;
typedef __attribute__((ext_vector_type(8))) __bf16 bf16x8;
typedef __attribute__((ext_vector_type(4))) float f32x4;
typedef __attribute__((ext_vector_type(4))) short s16x4;

constexpr int Bx = 2, Nx = 2048, MEMx = 2048, Jx = 4096, DIMx = 1024, Hx = 16, HDx = 64;

__device__ __forceinline__ void gload_lds16(const bf16_t* g, bf16_t* lds) {
  __builtin_amdgcn_global_load_lds(
      (const __attribute__((address_space(1))) unsigned int*)g,
      (__attribute__((address_space(3))) unsigned int*)lds, 16, 0, 0);
}

__device__ __forceinline__ f32x4 mfma16(bf16x4 a, bf16x4 b, f32x4 c) {
#if __has_builtin(__builtin_amdgcn_mfma_f32_16x16x16bf16_1k)
  return __builtin_amdgcn_mfma_f32_16x16x16bf16_1k(
      __builtin_bit_cast(s16x4, a), __builtin_bit_cast(s16x4, b), c, 0, 0, 0);
#else
  asm volatile("v_mfma_f32_16x16x16_bf16 %0, %1, %2, %0" : "+v"(c) : "v"(a), "v"(b));
  return c;
#endif
}

// ---------------- convert / pack kernels ----------------
__global__ void k_build_bf16(const float* __restrict__ x, const float* __restrict__ mem,
                             bf16_t* __restrict__ xb, bf16_t* __restrict__ ctxb) {
  const int XT = Bx * Nx * DIMx;
  const int CT = Bx * Jx * DIMx;
  for (int i = blockIdx.x * blockDim.x + threadIdx.x; i < XT + CT;
       i += gridDim.x * blockDim.x) {
    if (i < XT) {
      xb[i] = (bf16_t)x[i];
    } else {
      int c = i - XT;
      int bb = c / (Jx * DIMx);
      int rr = c % (Jx * DIMx);
      int j = rr / DIMx, d = rr % DIMx;
      float v = (j < MEMx) ? mem[(int64_t)(bb * MEMx + j) * DIMx + d]
                           : x[(int64_t)(bb * Nx + (j - MEMx)) * DIMx + d];
      ctxb[c] = (bf16_t)v;
    }
  }
}

__global__ void k_transpose_w(const float* __restrict__ W, bf16_t* __restrict__ WT,
                              int K, int Nc) {
  int total = K * Nc;
  for (int i = blockIdx.x * blockDim.x + threadIdx.x; i < total;
       i += gridDim.x * blockDim.x) {
    int n = i / K, k = i % K;
    WT[i] = (bf16_t)W[(int64_t)k * Nc + n];
  }
}

// ---------------- GEMM: C[M,Nc] = A[M,K] @ BT[Nc,K]^T ----------------
// scale: multiplied into every output (Q pre-scaling).
// gate:  if non-null, columns >= gate_col0 get v *= gate[row] (V pre-gating).
template <int OUTF32>
__launch_bounds__(256)
__global__ void k_gemm_bt(const bf16_t* __restrict__ A, const bf16_t* __restrict__ BT,
                          void* __restrict__ Cv, const float* __restrict__ bias,
                          const float* __restrict__ gate, int gate_col0, float scale,
                          int M, int Nc, int K) {
  __shared__ bf16_t As[128 * 32];
  __shared__ bf16_t Bs[128 * 32];
  const int tid = threadIdx.x;
  const int w = tid >> 6, l = tid & 63;
  const int lr = l & 15, lg = l >> 4;
  const int m0 = blockIdx.y * 128, n0 = blockIdx.x * 128;
  const int wm = (w >> 1) * 64, wn = (w & 1) * 64;

  const int srow = w * 16 + (l >> 2);
  const int scol = (l & 3) * 8;
  const bf16_t* ga0 = A + (int64_t)(m0 + srow) * K + scol;
  const bf16_t* gb0 = BT + (int64_t)(n0 + srow) * K + scol;
  bf16_t* lA = As + w * 512;
  bf16_t* lB = Bs + w * 512;

  f32x4 acc[4][4] = {};

  for (int k0 = 0; k0 < K; k0 += 32) {
    __syncthreads();
    gload_lds16(ga0 + k0, lA);
    gload_lds16(ga0 + (int64_t)64 * K + k0, lA + 2048);
    gload_lds16(gb0 + k0, lB);
    gload_lds16(gb0 + (int64_t)64 * K + k0, lB + 2048);
    __syncthreads();

    bf16x8 af[4], bfr[4];
#pragma unroll
    for (int t = 0; t < 4; ++t)
      af[t] = *(const bf16x8*)(As + (wm + t * 16 + lr) * 32 + lg * 8);
#pragma unroll
    for (int t = 0; t < 4; ++t)
      bfr[t] = *(const bf16x8*)(Bs + (wn + t * 16 + lr) * 32 + lg * 8);
#pragma unroll
    for (int mt = 0; mt < 4; ++mt)
#pragma unroll
      for (int nt = 0; nt < 4; ++nt)
        acc[mt][nt] = __builtin_amdgcn_mfma_f32_16x16x32_bf16(af[mt], bfr[nt],
                                                              acc[mt][nt], 0, 0, 0);
  }

#pragma unroll
  for (int mt = 0; mt < 4; ++mt) {
#pragma unroll
    for (int nt = 0; nt < 4; ++nt) {
      int col = n0 + wn + nt * 16 + lr;
#pragma unroll
      for (int r = 0; r < 4; ++r) {
        int row = m0 + wm + mt * 16 + lg * 4 + r;
        float v = acc[mt][nt][r] * scale;
        if (gate != nullptr && col >= gate_col0) v *= gate[row];
        if constexpr (OUTF32) {
          ((float*)Cv)[(int64_t)row * Nc + col] = v + bias[col];
        } else {
          ((bf16_t*)Cv)[(int64_t)row * Nc + col] = (bf16_t)v;
        }
      }
    }
  }
}

// ---------------- flash attention (swapped QK^T, in-register softmax) ----------
// grid: (N/64, H, B), 256 threads (4 waves x 16 q-rows). KV-tile 64, double-buffered.
// Q pre-scaled by 0.125*log2(e); V pre-gated. Defer-max online softmax.
__launch_bounds__(256)
__global__ void k_attn(const bf16_t* __restrict__ Q, const bf16_t* __restrict__ KV,
                       bf16_t* __restrict__ Hout) {
  __shared__ bf16_t Ks[2][64 * 64];   // swizzled: byte = j*128 + ((oct ^ (j&7))*16)
  __shared__ bf16_t Vs[2][64 * 80];   // V^T (pre-gated), pitch 160B, chunk ^= (d>>3)

  const int tid = threadIdx.x;
  const int w = tid >> 6, l = tid & 63;
  const int lr = l & 15, lg = l >> 4;
  const int b = blockIdx.z, h = blockIdx.y, q0 = blockIdx.x * 64;

  const bf16_t* Qb = Q + ((int64_t)b * Nx) * DIMx + h * HDx;
  const bf16_t* Kb = KV + ((int64_t)b * Jx) * (2 * DIMx) + h * HDx;
  const bf16_t* Vb = Kb + DIMx;

  const int qrow = q0 + w * 16 + lr;   // this lane's q (S^T column)

  // Q fragment as B-operand: col=q=lane&15, k(d) = kb*32 + lg*8 + jj
  bf16x8 qf[2];
#pragma unroll
  for (int kb = 0; kb < 2; ++kb)
    qf[kb] = *(const bf16x8*)(Qb + (int64_t)qrow * DIMx + kb * 32 + lg * 8);

  f32x4 o[4] = {};                 // O^T: d = nt*16 + lg*4 + r, q = lr
  float mrun = -1e30f, lsum = 0.f;

  const int ksrow = w * 16 + (l >> 3);
  const int kscol = ((l & 7) ^ (l >> 3)) * 8;   // inverse-swizzled global source
  const int jend = (Jx < q0 + 64 + MEMx) ? Jx : (q0 + 64 + MEMx);
  const int nt_tiles = jend >> 6;
  const f32x4 zf = {0.f, 0.f, 0.f, 0.f};

  auto stageK = [&](int bufi, int j0) {
    bf16_t* kd = &Ks[bufi][0] + w * 1024;
    const bf16_t* src = Kb + (int64_t)(j0 + ksrow) * 2048 + kscol;
    gload_lds16(src, kd);
    gload_lds16(src + (int64_t)8 * 2048, kd + 512);
  };
  auto stageV = [&](int bufi, int j0) {
#pragma unroll
    for (int t = 0; t < 2; ++t) {
      int vj = t * 32 + w * 8 + (l >> 3);
      int vd0 = (l & 7) * 8;
      bf16x8 vv = *(const bf16x8*)(Vb + (int64_t)(j0 + vj) * 2048 + vd0);
      int chx = ((t * 4 + w) ^ (l & 7)) * 16;  // (j>>3) ^ (d>>3)
#pragma unroll
      for (int i = 0; i < 8; ++i)
        *(bf16_t*)((char*)&Vs[bufi][0] + (vd0 + i) * 160 + chx + (l >> 3) * 2) = vv[i];
    }
  };

  stageK(0, 0);
  stageV(0, 0);
  __syncthreads();

  for (int t = 0; t < nt_tiles; ++t) {
    const int cur = t & 1;
    const int j0 = t << 6;
    if (t + 1 < nt_tiles) {          // prefetch next tile into the other buffer
      stageK(cur ^ 1, j0 + 64);
      stageV(cur ^ 1, j0 + 64);
    }
    const bf16_t* KsC = &Ks[cur][0];
    const char* VsC = (const char*)&Vs[cur][0];

    // S^T = K · Q^T   (A = K-tile: row=j=lane&15, k=d; B = Q^T)
    f32x4 s[4];
    __builtin_amdgcn_s_setprio(1);
#pragma unroll
    for (int jt = 0; jt < 4; ++jt) {
      bf16x8 kf0 = *(const bf16x8*)((const char*)KsC + (jt * 16 + lr) * 128 +
                                    ((lg ^ (lr & 7)) * 16));
      bf16x8 kf1 = *(const bf16x8*)((const char*)KsC + (jt * 16 + lr) * 128 +
                                    (((4 + lg) ^ (lr & 7)) * 16));
      f32x4 t0 = __builtin_amdgcn_mfma_f32_16x16x32_bf16(kf0, qf[0], zf, 0, 0, 0);
      s[jt] = __builtin_amdgcn_mfma_f32_16x16x32_bf16(kf1, qf[1], t0, 0, 0, 0);
    }
    __builtin_amdgcn_s_setprio(0);

    // causal mask (only the last tile of each block can be masked)
    if (j0 + 63 > q0 + MEMx) {
#pragma unroll
      for (int jt = 0; jt < 4; ++jt)
#pragma unroll
        for (int r = 0; r < 4; ++r) {
          int j = j0 + jt * 16 + lg * 4 + r;
          if (j > qrow + MEMx) s[jt][r] = -1e30f;
        }
    }

    // online softmax with defer-max (q is lane-local; S already in log2 units)
    float tm = s[0][0];
#pragma unroll
    for (int jt = 0; jt < 4; ++jt)
#pragma unroll
      for (int r = 0; r < 4; ++r) tm = fmaxf(tm, s[jt][r]);
    tm = fmaxf(tm, __shfl_xor(tm, 16));
    tm = fmaxf(tm, __shfl_xor(tm, 32));

    if (!__all(tm <= mrun + 8.f)) {
      float mnew = fmaxf(mrun, tm);
      float al = exp2f(mrun - mnew);
      mrun = mnew;
      lsum *= al;
#pragma unroll
      for (int nt = 0; nt < 4; ++nt)
#pragma unroll
        for (int r = 0; r < 4; ++r) o[nt][r] *= al;
    }

    float ps = 0.f;
#pragma unroll
    for (int jt = 0; jt < 4; ++jt)
#pragma unroll
      for (int r = 0; r < 4; ++r) {
        float p = exp2f(s[jt][r] - mrun);
        s[jt][r] = p;
        ps += p;
      }
    ps += __shfl_xor(ps, 16);
    ps += __shfl_xor(ps, 32);
    lsum += ps;

    // P^T fragments: k-layout of mfma16 B-operand == S^T D-layout (no lane moves)
    bf16x4 pf[4];
#pragma unroll
    for (int jt = 0; jt < 4; ++jt)
#pragma unroll
      for (int r = 0; r < 4; ++r) pf[jt][r] = (bf16_t)s[jt][r];

    // O^T += V^T · P^T  (A = V^T: row=d=lane&15, k=j = jt*16 + lg*4 + jj)
    __builtin_amdgcn_s_setprio(1);
#pragma unroll
    for (int nt = 0; nt < 4; ++nt) {
      int d = nt * 16 + lr;
#pragma unroll
      for (int jt = 0; jt < 4; ++jt) {
        bf16x4 vf = *(const bf16x4*)(VsC + d * 160 +
                                     (((jt * 2 + (lg >> 1)) ^ ((d >> 3) & 7)) * 16) +
                                     (lg & 1) * 8);
        o[nt] = mfma16(vf, pf[jt], o[nt]);
      }
    }
    __builtin_amdgcn_s_setprio(0);

    __syncthreads();   // next tile staged (vmcnt+lgkm drained); cur buffer free
  }

  // epilogue: O^T / l, store (q = lr lane-local; d = nt*16 + lg*4 + r)
  float inv = 1.f / lsum;
#pragma unroll
  for (int nt = 0; nt < 4; ++nt) {
    bf16x4 ov;
#pragma unroll
    for (int r = 0; r < 4; ++r) ov[r] = (bf16_t)(o[nt][r] * inv);
    *(bf16x4*)(Hout + (int64_t)(b * Nx + qrow) * DIMx + h * HDx + nt * 16 + lg * 4) = ov;
  }
}

// ---------------- launcher ----------------
extern "C" void kernel_launch(void* const* d_in, const int* in_sizes, int n_in,
                              void* d_out, int out_size, void* d_ws, size_t ws_size,
                              hipStream_t stream) {
  const float* x    = (const float*)d_in[0];
  const float* mem  = (const float*)d_in[1];
  const float* expm = (const float*)d_in[2];
  const float* Wq   = (const float*)d_in[3];
  const float* Wkv  = (const float*)d_in[4];
  const float* Wo   = (const float*)d_in[5];
  const float* bo   = (const float*)d_in[6];
  float* out = (float*)d_out;

  bf16_t* p = (bf16_t*)d_ws;
  bf16_t* xb   = p; p += (size_t)Bx * Nx * DIMx;
  bf16_t* ctxb = p; p += (size_t)Bx * Jx * DIMx;
  bf16_t* WqT  = p; p += (size_t)DIMx * DIMx;
  bf16_t* WkvT = p; p += (size_t)DIMx * 2 * DIMx;
  bf16_t* WoT  = p; p += (size_t)DIMx * DIMx;
  bf16_t* Qb   = p; p += (size_t)Bx * Nx * DIMx;
  bf16_t* KVb  = p; p += (size_t)Bx * Jx * 2 * DIMx;
  bf16_t* Ho   = p; p += (size_t)Bx * Nx * DIMx;

  k_build_bf16<<<4096, 256, 0, stream>>>(x, mem, xb, ctxb);
  k_transpose_w<<<1024, 256, 0, stream>>>(Wq, WqT, DIMx, DIMx);
  k_transpose_w<<<2048, 256, 0, stream>>>(Wkv, WkvT, DIMx, 2 * DIMx);
  k_transpose_w<<<1024, 256, 0, stream>>>(Wo, WoT, DIMx, DIMx);

  // Q: fold softmax scale (1/sqrt(64)) and log2(e) into the projection.
  const float qscale = 0.125f * 1.4426950408889634f;
  k_gemm_bt<0><<<dim3(1024 / 128, 4096 / 128), 256, 0, stream>>>(
      xb, WqT, Qb, nullptr, nullptr, 0x7fffffff, qscale, Bx * Nx, DIMx, DIMx);
  // KV: pre-gate the V half (columns >= DIMx) with expire_mask[b*J + j].
  k_gemm_bt<0><<<dim3(2048 / 128, 8192 / 128), 256, 0, stream>>>(
      ctxb, WkvT, KVb, nullptr, expm, DIMx, 1.0f, Bx * Jx, 2 * DIMx, DIMx);
  k_attn<<<dim3(Nx / 64, Hx, Bx), 256, 0, stream>>>(Qb, KVb, Ho);
  k_gemm_bt<1><<<dim3(1024 / 128, 4096 / 128), 256, 0, stream>>>(
      Ho, WoT, out, bo, nullptr, 0x7fffffff, 1.0f, Bx * Nx, DIMx, DIMx);
}

// Round 5
// 308.561 us; speedup vs baseline: 1.7154x; 1.0526x over previous
//
#include <hip/hip_runtime.h>
#include <cstdint>

typedef __bf16 bf16_t;
typedef __attribute__((ext_vector_type(2))) __bf16 bf16x2;
typedef __attribute__((ext_vector_type(4))) __bf16 bf16x4;
typedef __attribute__((ext_vector_type(8))) __bf16 bf16x8;
typedef __attribute__((ext_vector_type(4))) float f32x4;
typedef __attribute__((ext_vector_type(16))) float f32x16;
typedef __attribute__((ext_vector_type(4))) int i32x4;

constexpr int Bx = 2, Nx = 2048, MEMx = 2048, Jx = 4096, DIMx = 1024, Hx = 16, HDx = 64;

__device__ __forceinline__ void gload_lds16(const bf16_t* g, bf16_t* lds) {
  __builtin_amdgcn_global_load_lds(
      (const __attribute__((address_space(1))) unsigned int*)g,
      (__attribute__((address_space(3))) unsigned int*)lds, 16, 0, 0);
}

__device__ __forceinline__ int pk2(float a, float b) {
  bf16x2 t;
  t[0] = (bf16_t)a;
  t[1] = (bf16_t)b;
  return __builtin_bit_cast(int, t);
}

__device__ __forceinline__ void pl32swap(int& a, int& b) {
  asm volatile("v_permlane32_swap_b32 %0, %1" : "+v"(a), "+v"(b));
}

// ---------------- convert / pack kernels ----------------
__global__ void k_build_bf16(const float* __restrict__ x, const float* __restrict__ mem,
                             bf16_t* __restrict__ xb, bf16_t* __restrict__ ctxb) {
  const int XT = Bx * Nx * DIMx;
  const int CT = Bx * Jx * DIMx;
  for (int i = blockIdx.x * blockDim.x + threadIdx.x; i < XT + CT;
       i += gridDim.x * blockDim.x) {
    if (i < XT) {
      xb[i] = (bf16_t)x[i];
    } else {
      int c = i - XT;
      int bb = c / (Jx * DIMx);
      int rr = c % (Jx * DIMx);
      int j = rr / DIMx, d = rr % DIMx;
      float v = (j < MEMx) ? mem[(int64_t)(bb * MEMx + j) * DIMx + d]
                           : x[(int64_t)(bb * Nx + (j - MEMx)) * DIMx + d];
      ctxb[c] = (bf16_t)v;
    }
  }
}

__global__ void k_transpose_w(const float* __restrict__ W, bf16_t* __restrict__ WT,
                              int K, int Nc) {
  int total = K * Nc;
  for (int i = blockIdx.x * blockDim.x + threadIdx.x; i < total;
       i += gridDim.x * blockDim.x) {
    int n = i / K, k = i % K;
    WT[i] = (bf16_t)W[(int64_t)k * Nc + n];
  }
}

// ---------------- GEMM: C[M,Nc] = A[M,K] @ BT[Nc,K]^T ----------------
template <int OUTF32>
__launch_bounds__(256)
__global__ void k_gemm_bt(const bf16_t* __restrict__ A, const bf16_t* __restrict__ BT,
                          void* __restrict__ Cv, const float* __restrict__ bias,
                          const float* __restrict__ gate, int gate_col0, float scale,
                          int M, int Nc, int K) {
  __shared__ bf16_t As[128 * 32];
  __shared__ bf16_t Bs[128 * 32];
  const int tid = threadIdx.x;
  const int w = tid >> 6, l = tid & 63;
  const int lr = l & 15, lg = l >> 4;
  const int m0 = blockIdx.y * 128, n0 = blockIdx.x * 128;
  const int wm = (w >> 1) * 64, wn = (w & 1) * 64;

  const int srow = w * 16 + (l >> 2);
  const int scol = (l & 3) * 8;
  const bf16_t* ga0 = A + (int64_t)(m0 + srow) * K + scol;
  const bf16_t* gb0 = BT + (int64_t)(n0 + srow) * K + scol;
  bf16_t* lA = As + w * 512;
  bf16_t* lB = Bs + w * 512;

  f32x4 acc[4][4] = {};

  for (int k0 = 0; k0 < K; k0 += 32) {
    __syncthreads();
    gload_lds16(ga0 + k0, lA);
    gload_lds16(ga0 + (int64_t)64 * K + k0, lA + 2048);
    gload_lds16(gb0 + k0, lB);
    gload_lds16(gb0 + (int64_t)64 * K + k0, lB + 2048);
    __syncthreads();

    bf16x8 af[4], bfr[4];
#pragma unroll
    for (int t = 0; t < 4; ++t)
      af[t] = *(const bf16x8*)(As + (wm + t * 16 + lr) * 32 + lg * 8);
#pragma unroll
    for (int t = 0; t < 4; ++t)
      bfr[t] = *(const bf16x8*)(Bs + (wn + t * 16 + lr) * 32 + lg * 8);
#pragma unroll
    for (int mt = 0; mt < 4; ++mt)
#pragma unroll
      for (int nt = 0; nt < 4; ++nt)
        acc[mt][nt] = __builtin_amdgcn_mfma_f32_16x16x32_bf16(af[mt], bfr[nt],
                                                              acc[mt][nt], 0, 0, 0);
  }

#pragma unroll
  for (int mt = 0; mt < 4; ++mt) {
#pragma unroll
    for (int nt = 0; nt < 4; ++nt) {
      int col = n0 + wn + nt * 16 + lr;
#pragma unroll
      for (int r = 0; r < 4; ++r) {
        int row = m0 + wm + mt * 16 + lg * 4 + r;
        float v = acc[mt][nt][r] * scale;
        if (gate != nullptr && col >= gate_col0) v *= gate[row];
        if constexpr (OUTF32) {
          ((float*)Cv)[(int64_t)row * Nc + col] = v + bias[col];
        } else {
          ((bf16_t*)Cv)[(int64_t)row * Nc + col] = (bf16_t)v;
        }
      }
    }
  }
}

// ---------------- flash attention: 32x32 MFMA, swapped QK^T -----------------
// grid (N/128, H, B), 4 waves x 32 q-rows. KV-tile 64, double-buffered.
// S^T = mfma32(K, Q): q = lane&31, j = jb*32 + (r&3) + 8*(r>>2) + 4*(lane>>5).
// P redistributed to B-operand frags via cvt_pk + v_permlane32_swap (T12).
// O^T = mfma32(V^T, P^T): d = db*32 + (r&3) + 8*(r>>2) + 4*hi, q = lane&31.
__launch_bounds__(256)
__global__ void k_attn(const bf16_t* __restrict__ Q, const bf16_t* __restrict__ KV,
                       bf16_t* __restrict__ Hout) {
  __shared__ bf16_t Ks[2][64 * 64];   // byte = j*128 + ((chunk ^ (j&7))*16)
  __shared__ bf16_t Vs[2][64 * 80];   // V^T, pitch 160B, chunk ^= (d>>3)&7

  const int tid = threadIdx.x;
  const int w = tid >> 6, l = tid & 63;
  const int ql = l & 31, hi = l >> 5;
  const int b = blockIdx.z, h = blockIdx.y;
  // b-flip work balancing: paired blocks (c, c+256) get complementary causal depth
  const int qi = b ? (gridDim.x - 1 - blockIdx.x) : blockIdx.x;
  const int q0 = qi * 128;

  const bf16_t* Qb = Q + ((int64_t)b * Nx) * DIMx + h * HDx;
  const bf16_t* Kb = KV + ((int64_t)b * Jx) * (2 * DIMx) + h * HDx;
  const bf16_t* Vb = Kb + DIMx;

  const int qrow = q0 + w * 32 + ql;

  // Q as B-operand: col=q=lane&31, k(d) = dt*16 + hi*8 + jj
  bf16x8 qf[4];
#pragma unroll
  for (int dt = 0; dt < 4; ++dt)
    qf[dt] = *(const bf16x8*)(Qb + (int64_t)qrow * DIMx + dt * 16 + hi * 8);

  // loop-invariant LDS read offsets
  int koff[2][4], voff[2][4];
#pragma unroll
  for (int jb = 0; jb < 2; ++jb)
#pragma unroll
    for (int dt = 0; dt < 4; ++dt)
      koff[jb][dt] = (jb * 32 + ql) * 128 + (((dt * 2 + hi) * 16) ^ ((ql & 7) * 16));
#pragma unroll
  for (int db = 0; db < 2; ++db)
#pragma unroll
    for (int jt = 0; jt < 4; ++jt)
      voff[db][jt] = (db * 32 + ql) * 160 +
                     (((jt * 2 + hi) * 16) ^ (((db * 4 + (ql >> 3)) & 7) * 16));

  f32x16 o[2] = {};
  float mrun = -1e30f, lsum = 0.f;

  const int ksrow = w * 16 + (l >> 3);
  const int kscol = ((l & 7) ^ (l >> 3)) * 8;
  const int jend = (Jx < q0 + 128 + MEMx) ? Jx : (q0 + 128 + MEMx);
  const int nt_tiles = jend >> 6;
  const f32x16 z16 = {};

  auto stageK = [&](int bufi, int j0) {
    bf16_t* kd = &Ks[bufi][0] + w * 1024;
    const bf16_t* src = Kb + (int64_t)(j0 + ksrow) * 2048 + kscol;
    gload_lds16(src, kd);
    gload_lds16(src + (int64_t)8 * 2048, kd + 512);
  };
  auto stageV = [&](int bufi, int j0) {
#pragma unroll
    for (int t = 0; t < 2; ++t) {
      int vj = t * 32 + w * 8 + (l >> 3);
      int vd0 = (l & 7) * 8;
      bf16x8 vv = *(const bf16x8*)(Vb + (int64_t)(j0 + vj) * 2048 + vd0);
      int chx = ((t * 4 + w) ^ (l & 7)) * 16;  // (j>>3) ^ (d>>3)
#pragma unroll
      for (int i = 0; i < 8; ++i)
        *(bf16_t*)((char*)&Vs[bufi][0] + (vd0 + i) * 160 + chx + (l >> 3) * 2) = vv[i];
    }
  };

  stageK(0, 0);
  stageV(0, 0);
  __syncthreads();

  for (int t = 0; t < nt_tiles; ++t) {
    const int cur = t & 1;
    const int j0 = t << 6;
    if (t + 1 < nt_tiles) {
      stageK(cur ^ 1, j0 + 64);
      stageV(cur ^ 1, j0 + 64);
    }
    const char* KsC = (const char*)&Ks[cur][0];
    const char* VsC = (const char*)&Vs[cur][0];

    // S^T = K · Q^T  (A = K: row=j, k=d; B = Q^T)
    f32x16 s[2];
    __builtin_amdgcn_s_setprio(1);
#pragma unroll
    for (int jb = 0; jb < 2; ++jb) {
      f32x16 acc = z16;
#pragma unroll
      for (int dt = 0; dt < 4; ++dt) {
        bf16x8 kf = *(const bf16x8*)(KsC + koff[jb][dt]);
        acc = __builtin_amdgcn_mfma_f32_32x32x16_bf16(kf, qf[dt], acc, 0, 0, 0);
      }
      s[jb] = acc;
    }
    __builtin_amdgcn_s_setprio(0);

    // causal mask (only tiles near the diagonal)
    if (j0 + 63 > q0 + MEMx) {
#pragma unroll
      for (int jb = 0; jb < 2; ++jb)
#pragma unroll
        for (int r = 0; r < 16; ++r) {
          int j = j0 + jb * 32 + (r & 3) + (r >> 2) * 8 + hi * 4;
          if (j > qrow + MEMx) s[jb][r] = -1e30f;
        }
    }

    // online softmax with defer-max (q lane-local; log2 units already folded)
    f32x16 tv = __builtin_elementwise_max(s[0], s[1]);
    float t8[8], t4[4];
#pragma unroll
    for (int i = 0; i < 8; ++i) t8[i] = fmaxf(tv[i], tv[i + 8]);
#pragma unroll
    for (int i = 0; i < 4; ++i) t4[i] = fmaxf(t8[i], t8[i + 4]);
    float tm = fmaxf(fmaxf(t4[0], t4[1]), fmaxf(t4[2], t4[3]));
    tm = fmaxf(tm, __shfl_xor(tm, 32));

    if (!__all(tm <= mrun + 8.f)) {
      float mnew = fmaxf(mrun, tm);
      float al = exp2f(mrun - mnew);
      mrun = mnew;
      lsum *= al;
#pragma unroll
      for (int db = 0; db < 2; ++db)
#pragma unroll
        for (int r = 0; r < 16; ++r) o[db][r] *= al;
    }

#pragma unroll
    for (int jb = 0; jb < 2; ++jb)
#pragma unroll
      for (int r = 0; r < 16; ++r) s[jb][r] = exp2f(s[jb][r] - mrun);

    f32x16 av = s[0] + s[1];
    float a8[8], a4[4];
#pragma unroll
    for (int i = 0; i < 8; ++i) a8[i] = av[i] + av[i + 8];
#pragma unroll
    for (int i = 0; i < 4; ++i) a4[i] = a8[i] + a8[i + 4];
    float ps = (a4[0] + a4[1]) + (a4[2] + a4[3]);
    ps += __shfl_xor(ps, 32);
    lsum += ps;

    // P^T -> B-operand frags: cvt_pk pairs + permlane32 half-swaps (T12)
    bf16x8 pfrag[4];
#pragma unroll
    for (int jb = 0; jb < 2; ++jb) {
      int pw[8];
#pragma unroll
      for (int g = 0; g < 8; ++g) pw[g] = pk2(s[jb][2 * g], s[jb][2 * g + 1]);
      pl32swap(pw[0], pw[2]);
      pl32swap(pw[1], pw[3]);
      pl32swap(pw[4], pw[6]);
      pl32swap(pw[5], pw[7]);
      i32x4 f0 = {pw[0], pw[1], pw[2], pw[3]};
      i32x4 f1 = {pw[4], pw[5], pw[6], pw[7]};
      pfrag[jb * 2] = __builtin_bit_cast(bf16x8, f0);
      pfrag[jb * 2 + 1] = __builtin_bit_cast(bf16x8, f1);
    }

    // O^T += V^T · P^T  (A = V^T: row=d, k=j; B = P^T)
    __builtin_amdgcn_s_setprio(1);
#pragma unroll
    for (int db = 0; db < 2; ++db)
#pragma unroll
      for (int jt = 0; jt < 4; ++jt) {
        bf16x8 vf = *(const bf16x8*)(VsC + voff[db][jt]);
        o[db] = __builtin_amdgcn_mfma_f32_32x32x16_bf16(vf, pfrag[jt], o[db], 0, 0, 0);
      }
    __builtin_amdgcn_s_setprio(0);

    __syncthreads();   // prefetch drained; cur buffer reusable
  }

  // epilogue: O^T / l  (d = db*32 + (r&3) + (r>>2)*8 + hi*4, q = qrow)
  float inv = 1.f / lsum;
#pragma unroll
  for (int db = 0; db < 2; ++db)
#pragma unroll
    for (int g = 0; g < 4; ++g) {
      bf16x4 ov;
#pragma unroll
      for (int r = 0; r < 4; ++r) ov[r] = (bf16_t)(o[db][g * 4 + r] * inv);
      *(bf16x4*)(Hout + (int64_t)(b * Nx + qrow) * DIMx + h * HDx + db * 32 + g * 8 +
                 hi * 4) = ov;
    }
}

// ---------------- launcher ----------------
extern "C" void kernel_launch(void* const* d_in, const int* in_sizes, int n_in,
                              void* d_out, int out_size, void* d_ws, size_t ws_size,
                              hipStream_t stream) {
  const float* x    = (const float*)d_in[0];
  const float* mem  = (const float*)d_in[1];
  const float* expm = (const float*)d_in[2];
  const float* Wq   = (const float*)d_in[3];
  const float* Wkv  = (const float*)d_in[4];
  const float* Wo   = (const float*)d_in[5];
  const float* bo   = (const float*)d_in[6];
  float* out = (float*)d_out;

  bf16_t* p = (bf16_t*)d_ws;
  bf16_t* xb   = p; p += (size_t)Bx * Nx * DIMx;
  bf16_t* ctxb = p; p += (size_t)Bx * Jx * DIMx;
  bf16_t* WqT  = p; p += (size_t)DIMx * DIMx;
  bf16_t* WkvT = p; p += (size_t)DIMx * 2 * DIMx;
  bf16_t* WoT  = p; p += (size_t)DIMx * DIMx;
  bf16_t* Qb   = p; p += (size_t)Bx * Nx * DIMx;
  bf16_t* KVb  = p; p += (size_t)Bx * Jx * 2 * DIMx;
  bf16_t* Ho   = p; p += (size_t)Bx * Nx * DIMx;

  k_build_bf16<<<4096, 256, 0, stream>>>(x, mem, xb, ctxb);
  k_transpose_w<<<1024, 256, 0, stream>>>(Wq, WqT, DIMx, DIMx);
  k_transpose_w<<<2048, 256, 0, stream>>>(Wkv, WkvT, DIMx, 2 * DIMx);
  k_transpose_w<<<1024, 256, 0, stream>>>(Wo, WoT, DIMx, DIMx);

  const float qscale = 0.125f * 1.4426950408889634f;  // 1/sqrt(64) * log2(e)
  k_gemm_bt<0><<<dim3(1024 / 128, 4096 / 128), 256, 0, stream>>>(
      xb, WqT, Qb, nullptr, nullptr, 0x7fffffff, qscale, Bx * Nx, DIMx, DIMx);
  k_gemm_bt<0><<<dim3(2048 / 128, 8192 / 128), 256, 0, stream>>>(
      ctxb, WkvT, KVb, nullptr, expm, DIMx, 1.0f, Bx * Jx, 2 * DIMx, DIMx);
  k_attn<<<dim3(Nx / 128, Hx, Bx), 256, 0, stream>>>(Qb, KVb, Ho);
  k_gemm_bt<1><<<dim3(1024 / 128, 4096 / 128), 256, 0, stream>>>(
      Ho, WoT, out, bo, nullptr, 0x7fffffff, 1.0f, Bx * Nx, DIMx, DIMx);
}

// Round 6
// 302.032 us; speedup vs baseline: 1.7525x; 1.0216x over previous
//
#include <hip/hip_runtime.h>
#include <cstdint>

typedef __bf16 bf16_t;
typedef __attribute__((ext_vector_type(2))) __bf16 bf16x2;
typedef __attribute__((ext_vector_type(4))) __bf16 bf16x4;
typedef __attribute__((ext_vector_type(8))) __bf16 bf16x8;
typedef __attribute__((ext_vector_type(4))) float f32x4;
typedef __attribute__((ext_vector_type(16))) float f32x16;
typedef __attribute__((ext_vector_type(4))) int i32x4;

constexpr int Bx = 2, Nx = 2048, MEMx = 2048, Jx = 4096, DIMx = 1024, Hx = 16, HDx = 64;

__device__ __forceinline__ void gload_lds16(const bf16_t* g, bf16_t* lds) {
  __builtin_amdgcn_global_load_lds(
      (const __attribute__((address_space(1))) unsigned int*)g,
      (__attribute__((address_space(3))) unsigned int*)lds, 16, 0, 0);
}

__device__ __forceinline__ int pk2(float a, float b) {
  bf16x2 t;
  t[0] = (bf16_t)a;
  t[1] = (bf16_t)b;
  return __builtin_bit_cast(int, t);
}

__device__ __forceinline__ void pl32swap(int& a, int& b) {
  asm volatile("v_permlane32_swap_b32 %0, %1" : "+v"(a), "+v"(b));
}

// ---------------- convert / pack kernels ----------------
__global__ void k_build_bf16(const float* __restrict__ x, const float* __restrict__ mem,
                             bf16_t* __restrict__ xb, bf16_t* __restrict__ ctxb) {
  const int XT = Bx * Nx * DIMx;
  const int CT = Bx * Jx * DIMx;
  for (int i = blockIdx.x * blockDim.x + threadIdx.x; i < XT + CT;
       i += gridDim.x * blockDim.x) {
    if (i < XT) {
      xb[i] = (bf16_t)x[i];
    } else {
      int c = i - XT;
      int bb = c / (Jx * DIMx);
      int rr = c % (Jx * DIMx);
      int j = rr / DIMx, d = rr % DIMx;
      float v = (j < MEMx) ? mem[(int64_t)(bb * MEMx + j) * DIMx + d]
                           : x[(int64_t)(bb * Nx + (j - MEMx)) * DIMx + d];
      ctxb[c] = (bf16_t)v;
    }
  }
}

__global__ void k_transpose_w(const float* __restrict__ W, bf16_t* __restrict__ WT,
                              int K, int Nc) {
  int total = K * Nc;
  for (int i = blockIdx.x * blockDim.x + threadIdx.x; i < total;
       i += gridDim.x * blockDim.x) {
    int n = i / K, k = i % K;
    WT[i] = (bf16_t)W[(int64_t)k * Nc + n];
  }
}

// ---------------- GEMM: C[M,Nc] = A[M,K] @ BT[Nc,K]^T ----------------
// T3-minimum 2-phase: double-buffered BK=32, prefetch issued BEFORE compute,
// single barrier per K-step (barrier vmcnt-drain completes the prefetch DMA).
template <int OUTF32>
__launch_bounds__(256)
__global__ void k_gemm_bt(const bf16_t* __restrict__ A, const bf16_t* __restrict__ BT,
                          void* __restrict__ Cv, const float* __restrict__ bias,
                          const float* __restrict__ gate, int gate_col0, float scale,
                          int M, int Nc, int K) {
  __shared__ bf16_t As[2][128 * 32];
  __shared__ bf16_t Bs[2][128 * 32];
  const int tid = threadIdx.x;
  const int w = tid >> 6, l = tid & 63;
  const int lr = l & 15, lg = l >> 4;
  const int m0 = blockIdx.y * 128, n0 = blockIdx.x * 128;
  const int wm = (w >> 1) * 64, wn = (w & 1) * 64;

  const int srow = w * 16 + (l >> 2);
  const int scol = (l & 3) * 8;
  const bf16_t* ga0 = A + (int64_t)(m0 + srow) * K + scol;
  const bf16_t* gb0 = BT + (int64_t)(n0 + srow) * K + scol;

  auto stage = [&](int bufi, int k0) {
    bf16_t* lA = &As[bufi][0] + w * 512;
    bf16_t* lB = &Bs[bufi][0] + w * 512;
    gload_lds16(ga0 + k0, lA);
    gload_lds16(ga0 + (int64_t)64 * K + k0, lA + 2048);
    gload_lds16(gb0 + k0, lB);
    gload_lds16(gb0 + (int64_t)64 * K + k0, lB + 2048);
  };

  f32x4 acc[4][4] = {};

  stage(0, 0);
  __syncthreads();

  const int nsteps = K >> 5;
  for (int t = 0; t < nsteps; ++t) {
    const int cur = t & 1;
    if (t + 1 < nsteps) stage(cur ^ 1, (t + 1) << 5);

    bf16x8 af[4], bfr[4];
#pragma unroll
    for (int q = 0; q < 4; ++q)
      af[q] = *(const bf16x8*)(&As[cur][0] + (wm + q * 16 + lr) * 32 + lg * 8);
#pragma unroll
    for (int q = 0; q < 4; ++q)
      bfr[q] = *(const bf16x8*)(&Bs[cur][0] + (wn + q * 16 + lr) * 32 + lg * 8);
#pragma unroll
    for (int mt = 0; mt < 4; ++mt)
#pragma unroll
      for (int nt = 0; nt < 4; ++nt)
        acc[mt][nt] = __builtin_amdgcn_mfma_f32_16x16x32_bf16(af[mt], bfr[nt],
                                                              acc[mt][nt], 0, 0, 0);
    __syncthreads();
  }

#pragma unroll
  for (int mt = 0; mt < 4; ++mt) {
#pragma unroll
    for (int nt = 0; nt < 4; ++nt) {
      int col = n0 + wn + nt * 16 + lr;
#pragma unroll
      for (int r = 0; r < 4; ++r) {
        int row = m0 + wm + mt * 16 + lg * 4 + r;
        float v = acc[mt][nt][r] * scale;
        if (gate != nullptr && col >= gate_col0) v *= gate[row];
        if constexpr (OUTF32) {
          ((float*)Cv)[(int64_t)row * Nc + col] = v + bias[col];
        } else {
          ((bf16_t*)Cv)[(int64_t)row * Nc + col] = (bf16_t)v;
        }
      }
    }
  }
}

// ---------------- flash attention: 32x32 MFMA, swapped QK^T -----------------
// grid (N/128, H, B), 4 waves x 32 q-rows. KV-tile 64, double-buffered.
// T14 async-STAGE: K via global_load_lds DMA; V global->regs issued at loop
// top, ds_write'd AFTER compute; ONE barrier per tile.
__launch_bounds__(256)
__global__ void k_attn(const bf16_t* __restrict__ Q, const bf16_t* __restrict__ KV,
                       bf16_t* __restrict__ Hout) {
  __shared__ bf16_t Ks[2][64 * 64];   // byte = j*128 + ((chunk ^ (j&7))*16)
  __shared__ bf16_t Vs[2][64 * 80];   // V^T, pitch 160B, chunk ^= (d>>3)&7

  const int tid = threadIdx.x;
  const int w = tid >> 6, l = tid & 63;
  const int ql = l & 31, hi = l >> 5;
  const int b = blockIdx.z, h = blockIdx.y;
  const int qi = b ? (gridDim.x - 1 - blockIdx.x) : blockIdx.x;  // causal balance
  const int q0 = qi * 128;

  const bf16_t* Qb = Q + ((int64_t)b * Nx) * DIMx + h * HDx;
  const bf16_t* Kb = KV + ((int64_t)b * Jx) * (2 * DIMx) + h * HDx;
  const bf16_t* Vb = Kb + DIMx;

  const int qrow = q0 + w * 32 + ql;

  bf16x8 qf[4];
#pragma unroll
  for (int dt = 0; dt < 4; ++dt)
    qf[dt] = *(const bf16x8*)(Qb + (int64_t)qrow * DIMx + dt * 16 + hi * 8);

  // loop-invariant LDS read offsets
  int koff[2][4], voff[2][4];
#pragma unroll
  for (int jb = 0; jb < 2; ++jb)
#pragma unroll
    for (int dt = 0; dt < 4; ++dt)
      koff[jb][dt] = (jb * 32 + ql) * 128 + (((dt * 2 + hi) * 16) ^ ((ql & 7) * 16));
#pragma unroll
  for (int db = 0; db < 2; ++db)
#pragma unroll
    for (int jt = 0; jt < 4; ++jt)
      voff[db][jt] = (db * 32 + ql) * 160 +
                     (((jt * 2 + hi) * 16) ^ (((db * 4 + (ql >> 3)) & 7) * 16));

  f32x16 o[2] = {};
  float mrun = -1e30f, lsum = 0.f;

  const int ksrow = w * 16 + (l >> 3);
  const int kscol = ((l & 7) ^ (l >> 3)) * 8;
  const int jend = (Jx < q0 + 128 + MEMx) ? Jx : (q0 + 128 + MEMx);
  const int nt_tiles = jend >> 6;
  const f32x16 z16 = {};

  // V staging geometry (tile-invariant)
  const bf16_t* vsrc0 = Vb + (int64_t)(w * 8 + (l >> 3)) * 2048 + (l & 7) * 8;
  const int vd0 = (l & 7) * 8;
  const int vrow2 = (l >> 3) * 2;
  const int chx0 = ((w) ^ (l & 7)) * 16;
  const int chx1 = ((4 + w) ^ (l & 7)) * 16;

  auto stageK = [&](int bufi, int j0) {
    bf16_t* kd = &Ks[bufi][0] + w * 1024;
    const bf16_t* src = Kb + (int64_t)(j0 + ksrow) * 2048 + kscol;
    gload_lds16(src, kd);
    gload_lds16(src + (int64_t)8 * 2048, kd + 512);
  };
  auto loadV = [&](int j0, bf16x8& a, bf16x8& c) {
    const bf16_t* s = vsrc0 + (int64_t)j0 * 2048;
    a = *(const bf16x8*)s;
    c = *(const bf16x8*)(s + (int64_t)32 * 2048);
  };
  auto writeV = [&](int bufi, bf16x8 a, bf16x8 c) {
    char* base = (char*)&Vs[bufi][0];
#pragma unroll
    for (int i = 0; i < 8; ++i)
      *(bf16_t*)(base + (vd0 + i) * 160 + chx0 + vrow2) = a[i];
#pragma unroll
    for (int i = 0; i < 8; ++i)
      *(bf16_t*)(base + (vd0 + i) * 160 + chx1 + vrow2) = c[i];
  };

  // prologue: tile 0
  bf16x8 vA, vC;
  stageK(0, 0);
  loadV(0, vA, vC);
  writeV(0, vA, vC);      // compiler inserts vmcnt wait before ds_write
  __syncthreads();        // drains K-DMA; Vs[0] visible

  for (int t = 0; t < nt_tiles; ++t) {
    const int cur = t & 1;
    const int j0 = t << 6;
    const bool pf = (t + 1 < nt_tiles);
    if (pf) {
      stageK(cur ^ 1, j0 + 64);   // DMA, completes at barrier drain
      loadV(j0 + 64, vA, vC);     // issue only; consumed after PV
    }
    const char* KsC = (const char*)&Ks[cur][0];
    const char* VsC = (const char*)&Vs[cur][0];

    // S^T = K · Q^T
    f32x16 s[2];
    __builtin_amdgcn_s_setprio(1);
#pragma unroll
    for (int jb = 0; jb < 2; ++jb) {
      f32x16 acc = z16;
#pragma unroll
      for (int dt = 0; dt < 4; ++dt) {
        bf16x8 kf = *(const bf16x8*)(KsC + koff[jb][dt]);
        acc = __builtin_amdgcn_mfma_f32_32x32x16_bf16(kf, qf[dt], acc, 0, 0, 0);
      }
      s[jb] = acc;
    }
    __builtin_amdgcn_s_setprio(0);

    if (j0 + 63 > q0 + MEMx) {
#pragma unroll
      for (int jb = 0; jb < 2; ++jb)
#pragma unroll
        for (int r = 0; r < 16; ++r) {
          int j = j0 + jb * 32 + (r & 3) + (r >> 2) * 8 + hi * 4;
          if (j > qrow + MEMx) s[jb][r] = -1e30f;
        }
    }

    // online softmax, defer-max (log2 units folded into Q)
    f32x16 tv = __builtin_elementwise_max(s[0], s[1]);
    float t8[8], t4[4];
#pragma unroll
    for (int i = 0; i < 8; ++i) t8[i] = fmaxf(tv[i], tv[i + 8]);
#pragma unroll
    for (int i = 0; i < 4; ++i) t4[i] = fmaxf(t8[i], t8[i + 4]);
    float tm = fmaxf(fmaxf(t4[0], t4[1]), fmaxf(t4[2], t4[3]));
    tm = fmaxf(tm, __shfl_xor(tm, 32));

    if (!__all(tm <= mrun + 8.f)) {
      float mnew = fmaxf(mrun, tm);
      float al = exp2f(mrun - mnew);
      mrun = mnew;
      lsum *= al;
#pragma unroll
      for (int db = 0; db < 2; ++db)
#pragma unroll
        for (int r = 0; r < 16; ++r) o[db][r] *= al;
    }

#pragma unroll
    for (int jb = 0; jb < 2; ++jb)
#pragma unroll
      for (int r = 0; r < 16; ++r) s[jb][r] = exp2f(s[jb][r] - mrun);

    f32x16 av = s[0] + s[1];
    float a8[8], a4[4];
#pragma unroll
    for (int i = 0; i < 8; ++i) a8[i] = av[i] + av[i + 8];
#pragma unroll
    for (int i = 0; i < 4; ++i) a4[i] = a8[i] + a8[i + 4];
    float ps = (a4[0] + a4[1]) + (a4[2] + a4[3]);
    ps += __shfl_xor(ps, 32);
    lsum += ps;

    // P^T -> B-operand frags (cvt_pk pairs + permlane32 half-swaps, T12)
    bf16x8 pfrag[4];
#pragma unroll
    for (int jb = 0; jb < 2; ++jb) {
      int pw[8];
#pragma unroll
      for (int g = 0; g < 8; ++g) pw[g] = pk2(s[jb][2 * g], s[jb][2 * g + 1]);
      pl32swap(pw[0], pw[2]);
      pl32swap(pw[1], pw[3]);
      pl32swap(pw[4], pw[6]);
      pl32swap(pw[5], pw[7]);
      i32x4 f0 = {pw[0], pw[1], pw[2], pw[3]};
      i32x4 f1 = {pw[4], pw[5], pw[6], pw[7]};
      pfrag[jb * 2] = __builtin_bit_cast(bf16x8, f0);
      pfrag[jb * 2 + 1] = __builtin_bit_cast(bf16x8, f1);
    }

    // O^T += V^T · P^T
    __builtin_amdgcn_s_setprio(1);
#pragma unroll
    for (int db = 0; db < 2; ++db)
#pragma unroll
      for (int jt = 0; jt < 4; ++jt) {
        bf16x8 vf = *(const bf16x8*)(VsC + voff[db][jt]);
        o[db] = __builtin_amdgcn_mfma_f32_32x32x16_bf16(vf, pfrag[jt], o[db], 0, 0, 0);
      }
    __builtin_amdgcn_s_setprio(0);

    // write next tile's V (vmcnt wait lands here, after ~full tile of compute)
    if (pf) writeV(cur ^ 1, vA, vC);
    __syncthreads();   // one barrier/tile: drains K-DMA + V ds_writes
  }

  // epilogue: O^T / l
  float inv = 1.f / lsum;
#pragma unroll
  for (int db = 0; db < 2; ++db)
#pragma unroll
    for (int g = 0; g < 4; ++g) {
      bf16x4 ov;
#pragma unroll
      for (int r = 0; r < 4; ++r) ov[r] = (bf16_t)(o[db][g * 4 + r] * inv);
      *(bf16x4*)(Hout + (int64_t)(b * Nx + qrow) * DIMx + h * HDx + db * 32 + g * 8 +
                 hi * 4) = ov;
    }
}

// ---------------- launcher ----------------
extern "C" void kernel_launch(void* const* d_in, const int* in_sizes, int n_in,
                              void* d_out, int out_size, void* d_ws, size_t ws_size,
                              hipStream_t stream) {
  const float* x    = (const float*)d_in[0];
  const float* mem  = (const float*)d_in[1];
  const float* expm = (const float*)d_in[2];
  const float* Wq   = (const float*)d_in[3];
  const float* Wkv  = (const float*)d_in[4];
  const float* Wo   = (const float*)d_in[5];
  const float* bo   = (const float*)d_in[6];
  float* out = (float*)d_out;

  bf16_t* p = (bf16_t*)d_ws;
  bf16_t* xb   = p; p += (size_t)Bx * Nx * DIMx;
  bf16_t* ctxb = p; p += (size_t)Bx * Jx * DIMx;
  bf16_t* WqT  = p; p += (size_t)DIMx * DIMx;
  bf16_t* WkvT = p; p += (size_t)DIMx * 2 * DIMx;
  bf16_t* WoT  = p; p += (size_t)DIMx * DIMx;
  bf16_t* Qb   = p; p += (size_t)Bx * Nx * DIMx;
  bf16_t* KVb  = p; p += (size_t)Bx * Jx * 2 * DIMx;
  bf16_t* Ho   = p; p += (size_t)Bx * Nx * DIMx;

  k_build_bf16<<<4096, 256, 0, stream>>>(x, mem, xb, ctxb);
  k_transpose_w<<<1024, 256, 0, stream>>>(Wq, WqT, DIMx, DIMx);
  k_transpose_w<<<2048, 256, 0, stream>>>(Wkv, WkvT, DIMx, 2 * DIMx);
  k_transpose_w<<<1024, 256, 0, stream>>>(Wo, WoT, DIMx, DIMx);

  const float qscale = 0.125f * 1.4426950408889634f;  // 1/sqrt(64) * log2(e)
  k_gemm_bt<0><<<dim3(1024 / 128, 4096 / 128), 256, 0, stream>>>(
      xb, WqT, Qb, nullptr, nullptr, 0x7fffffff, qscale, Bx * Nx, DIMx, DIMx);
  k_gemm_bt<0><<<dim3(2048 / 128, 8192 / 128), 256, 0, stream>>>(
      ctxb, WkvT, KVb, nullptr, expm, DIMx, 1.0f, Bx * Jx, 2 * DIMx, DIMx);
  k_attn<<<dim3(Nx / 128, Hx, Bx), 256, 0, stream>>>(Qb, KVb, Ho);
  k_gemm_bt<1><<<dim3(1024 / 128, 4096 / 128), 256, 0, stream>>>(
      Ho, WoT, out, bo, nullptr, 0x7fffffff, 1.0f, Bx * Nx, DIMx, DIMx);
}

// Round 7
// 301.045 us; speedup vs baseline: 1.7582x; 1.0033x over previous
//
#include <hip/hip_runtime.h>
#include <cstdint>

typedef __bf16 bf16_t;
typedef __attribute__((ext_vector_type(2))) __bf16 bf16x2;
typedef __attribute__((ext_vector_type(4))) __bf16 bf16x4;
typedef __attribute__((ext_vector_type(8))) __bf16 bf16x8;
typedef __attribute__((ext_vector_type(4))) float f32x4;
typedef __attribute__((ext_vector_type(16))) float f32x16;
typedef __attribute__((ext_vector_type(4))) int i32x4;

constexpr int Bx = 2, Nx = 2048, MEMx = 2048, Jx = 4096, DIMx = 1024, Hx = 16, HDx = 64;

__device__ __forceinline__ void gload_lds16(const bf16_t* g, bf16_t* lds) {
  __builtin_amdgcn_global_load_lds(
      (const __attribute__((address_space(1))) unsigned int*)g,
      (__attribute__((address_space(3))) unsigned int*)lds, 16, 0, 0);
}

__device__ __forceinline__ int pk2(float a, float b) {
  bf16x2 t;
  t[0] = (bf16_t)a;
  t[1] = (bf16_t)b;
  return __builtin_bit_cast(int, t);
}

__device__ __forceinline__ void pl32swap(int& a, int& b) {
  asm volatile("v_permlane32_swap_b32 %0, %1" : "+v"(a), "+v"(b));
}

__device__ __forceinline__ float fmax3(float a, float b, float c) {
  float d;
  asm("v_max3_f32 %0, %1, %2, %3" : "=v"(d) : "v"(a), "v"(b), "v"(c));
  return d;
}

// ---------------- convert / pack kernels ----------------
__global__ void k_build_bf16(const float* __restrict__ x, const float* __restrict__ mem,
                             bf16_t* __restrict__ xb, bf16_t* __restrict__ ctxb) {
  const int XT = Bx * Nx * DIMx;
  const int CT = Bx * Jx * DIMx;
  for (int i = blockIdx.x * blockDim.x + threadIdx.x; i < XT + CT;
       i += gridDim.x * blockDim.x) {
    if (i < XT) {
      xb[i] = (bf16_t)x[i];
    } else {
      int c = i - XT;
      int bb = c / (Jx * DIMx);
      int rr = c % (Jx * DIMx);
      int j = rr / DIMx, d = rr % DIMx;
      float v = (j < MEMx) ? mem[(int64_t)(bb * MEMx + j) * DIMx + d]
                           : x[(int64_t)(bb * Nx + (j - MEMx)) * DIMx + d];
      ctxb[c] = (bf16_t)v;
    }
  }
}

__global__ void k_transpose_w(const float* __restrict__ W, bf16_t* __restrict__ WT,
                              int K, int Nc) {
  int total = K * Nc;
  for (int i = blockIdx.x * blockDim.x + threadIdx.x; i < total;
       i += gridDim.x * blockDim.x) {
    int n = i / K, k = i % K;
    WT[i] = (bf16_t)W[(int64_t)k * Nc + n];
  }
}

// ---------------- GEMM: C[M,Nc] = A[M,K] @ BT[Nc,K]^T (2-phase prefetch) ------
template <int OUTF32>
__launch_bounds__(256)
__global__ void k_gemm_bt(const bf16_t* __restrict__ A, const bf16_t* __restrict__ BT,
                          void* __restrict__ Cv, const float* __restrict__ bias,
                          const float* __restrict__ gate, int gate_col0, float scale,
                          int M, int Nc, int K) {
  __shared__ bf16_t As[2][128 * 32];
  __shared__ bf16_t Bs[2][128 * 32];
  const int tid = threadIdx.x;
  const int w = tid >> 6, l = tid & 63;
  const int lr = l & 15, lg = l >> 4;
  const int m0 = blockIdx.y * 128, n0 = blockIdx.x * 128;
  const int wm = (w >> 1) * 64, wn = (w & 1) * 64;

  const int srow = w * 16 + (l >> 2);
  const int scol = (l & 3) * 8;
  const bf16_t* ga0 = A + (int64_t)(m0 + srow) * K + scol;
  const bf16_t* gb0 = BT + (int64_t)(n0 + srow) * K + scol;

  auto stage = [&](int bufi, int k0) {
    bf16_t* lA = &As[bufi][0] + w * 512;
    bf16_t* lB = &Bs[bufi][0] + w * 512;
    gload_lds16(ga0 + k0, lA);
    gload_lds16(ga0 + (int64_t)64 * K + k0, lA + 2048);
    gload_lds16(gb0 + k0, lB);
    gload_lds16(gb0 + (int64_t)64 * K + k0, lB + 2048);
  };

  f32x4 acc[4][4] = {};

  stage(0, 0);
  __syncthreads();

  const int nsteps = K >> 5;
  for (int t = 0; t < nsteps; ++t) {
    const int cur = t & 1;
    if (t + 1 < nsteps) stage(cur ^ 1, (t + 1) << 5);

    bf16x8 af[4], bfr[4];
#pragma unroll
    for (int q = 0; q < 4; ++q)
      af[q] = *(const bf16x8*)(&As[cur][0] + (wm + q * 16 + lr) * 32 + lg * 8);
#pragma unroll
    for (int q = 0; q < 4; ++q)
      bfr[q] = *(const bf16x8*)(&Bs[cur][0] + (wn + q * 16 + lr) * 32 + lg * 8);
#pragma unroll
    for (int mt = 0; mt < 4; ++mt)
#pragma unroll
      for (int nt = 0; nt < 4; ++nt)
        acc[mt][nt] = __builtin_amdgcn_mfma_f32_16x16x32_bf16(af[mt], bfr[nt],
                                                              acc[mt][nt], 0, 0, 0);
    __syncthreads();
  }

#pragma unroll
  for (int mt = 0; mt < 4; ++mt) {
#pragma unroll
    for (int nt = 0; nt < 4; ++nt) {
      int col = n0 + wn + nt * 16 + lr;
#pragma unroll
      for (int r = 0; r < 4; ++r) {
        int row = m0 + wm + mt * 16 + lg * 4 + r;
        float v = acc[mt][nt][r] * scale;
        if (gate != nullptr && col >= gate_col0) v *= gate[row];
        if constexpr (OUTF32) {
          ((float*)Cv)[(int64_t)row * Nc + col] = v + bias[col];
        } else {
          ((bf16_t*)Cv)[(int64_t)row * Nc + col] = (bf16_t)v;
        }
      }
    }
  }
}

// ---------------- flash attention, J-chunked (flash-decoding style) ----------
// 1024 blocks: bits[3:0]=qi, [7:4]=h, [8]=chunk, [9]=b (CU families mix chunks).
// Each block: 4 waves x 32 q-rows, KV-tile 64 double-buffered, j in
// [c*2048, jend). Writes un-normalized O^T (bf16) + (m,l) per q; k_combine merges.
__launch_bounds__(256)
__global__ void k_attn(const bf16_t* __restrict__ Q, const bf16_t* __restrict__ KV,
                       bf16_t* __restrict__ Opart, float2* __restrict__ ML) {
  __shared__ bf16_t Ks[2][64 * 64];   // byte = j*128 + ((chunk ^ (j&7))*16)
  __shared__ bf16_t Vs[2][64 * 80];   // V^T, pitch 160B, chunk ^= (d>>3)&7

  const int tid = threadIdx.x;
  const int w = tid >> 6, l = tid & 63;
  const int ql = l & 31, hi = l >> 5;

  const int lin = blockIdx.x;
  const int qi0 = lin & 15, h = (lin >> 4) & 15;
  const int c = (lin >> 8) & 1, b = lin >> 9;
  const int qi = b ? (15 - qi0) : qi0;   // causal-depth pairing within CU family
  const int q0 = qi * 128;

  const bf16_t* Qb = Q + ((int64_t)b * Nx) * DIMx + h * HDx;
  const bf16_t* Kb = KV + ((int64_t)b * Jx) * (2 * DIMx) + h * HDx;
  const bf16_t* Vb = Kb + DIMx;

  const int qrow = q0 + w * 32 + ql;

  bf16x8 qf[4];
#pragma unroll
  for (int dt = 0; dt < 4; ++dt)
    qf[dt] = *(const bf16x8*)(Qb + (int64_t)qrow * DIMx + dt * 16 + hi * 8);

  int koff[2][4], voff[2][4];
#pragma unroll
  for (int jb = 0; jb < 2; ++jb)
#pragma unroll
    for (int dt = 0; dt < 4; ++dt)
      koff[jb][dt] = (jb * 32 + ql) * 128 + (((dt * 2 + hi) * 16) ^ ((ql & 7) * 16));
#pragma unroll
  for (int db = 0; db < 2; ++db)
#pragma unroll
    for (int jt = 0; jt < 4; ++jt)
      voff[db][jt] = (db * 32 + ql) * 160 +
                     (((jt * 2 + hi) * 16) ^ (((db * 4 + (ql >> 3)) & 7) * 16));

  f32x16 o[2] = {};
  float mrun = -1e30f, lsum = 0.f;

  const int ksrow = w * 16 + (l >> 3);
  const int kscol = ((l & 7) ^ (l >> 3)) * 8;
  const int jstart = c * 2048;
  const int jend = c ? ((Jx < q0 + 128 + MEMx) ? Jx : (q0 + 128 + MEMx)) : 2048;
  const int nt_tiles = (jend - jstart) >> 6;
  const f32x16 z16 = {};

  const bf16_t* vsrc0 = Vb + (int64_t)(w * 8 + (l >> 3)) * 2048 + (l & 7) * 8;
  const int vd0 = (l & 7) * 8;
  const int vrow2 = (l >> 3) * 2;
  const int chx0 = ((w) ^ (l & 7)) * 16;
  const int chx1 = ((4 + w) ^ (l & 7)) * 16;

  auto stageK = [&](int bufi, int j0) {
    bf16_t* kd = &Ks[bufi][0] + w * 1024;
    const bf16_t* src = Kb + (int64_t)(j0 + ksrow) * 2048 + kscol;
    gload_lds16(src, kd);
    gload_lds16(src + (int64_t)8 * 2048, kd + 512);
  };
  auto loadV = [&](int j0, bf16x8& a, bf16x8& cc) {
    const bf16_t* s = vsrc0 + (int64_t)j0 * 2048;
    a = *(const bf16x8*)s;
    cc = *(const bf16x8*)(s + (int64_t)32 * 2048);
  };
  auto writeV = [&](int bufi, bf16x8 a, bf16x8 cc) {
    char* base = (char*)&Vs[bufi][0];
#pragma unroll
    for (int i = 0; i < 8; ++i)
      *(bf16_t*)(base + (vd0 + i) * 160 + chx0 + vrow2) = a[i];
#pragma unroll
    for (int i = 0; i < 8; ++i)
      *(bf16_t*)(base + (vd0 + i) * 160 + chx1 + vrow2) = cc[i];
  };

  bf16x8 vA, vC;
  stageK(0, jstart);
  loadV(jstart, vA, vC);
  writeV(0, vA, vC);
  __syncthreads();

  for (int t = 0; t < nt_tiles; ++t) {
    const int cur = t & 1;
    const int j0 = jstart + (t << 6);
    const bool pf = (t + 1 < nt_tiles);
    if (pf) {
      stageK(cur ^ 1, j0 + 64);
      loadV(j0 + 64, vA, vC);
    }
    const char* KsC = (const char*)&Ks[cur][0];
    const char* VsC = (const char*)&Vs[cur][0];

    // S^T = K · Q^T
    f32x16 s[2];
    __builtin_amdgcn_s_setprio(1);
#pragma unroll
    for (int jb = 0; jb < 2; ++jb) {
      f32x16 acc = z16;
#pragma unroll
      for (int dt = 0; dt < 4; ++dt) {
        bf16x8 kf = *(const bf16x8*)(KsC + koff[jb][dt]);
        acc = __builtin_amdgcn_mfma_f32_32x32x16_bf16(kf, qf[dt], acc, 0, 0, 0);
      }
      s[jb] = acc;
    }
    __builtin_amdgcn_s_setprio(0);

    if (j0 + 63 > q0 + MEMx) {   // self-disables for chunk 0
#pragma unroll
      for (int jb = 0; jb < 2; ++jb)
#pragma unroll
        for (int r = 0; r < 16; ++r) {
          int j = j0 + jb * 32 + (r & 3) + (r >> 2) * 8 + hi * 4;
          if (j > qrow + MEMx) s[jb][r] = -1e30f;
        }
    }

    // tile max via v_max3 tree (16 ops) + 1 shfl
    float t12[12];
#pragma unroll
    for (int i = 0; i < 10; ++i)
      t12[i] = fmax3(s[(3 * i) >> 4][(3 * i) & 15], s[(3 * i + 1) >> 4][(3 * i + 1) & 15],
                     s[(3 * i + 2) >> 4][(3 * i + 2) & 15]);
    t12[10] = s[1][14];
    t12[11] = s[1][15];
    float t4[4];
#pragma unroll
    for (int i = 0; i < 4; ++i) t4[i] = fmax3(t12[3 * i], t12[3 * i + 1], t12[3 * i + 2]);
    float tm = fmaxf(fmax3(t4[0], t4[1], t4[2]), t4[3]);
    tm = fmaxf(tm, __shfl_xor(tm, 32));

    if (!__all(tm <= mrun + 8.f)) {
      float mnew = fmaxf(mrun, tm);
      float al = exp2f(mrun - mnew);
      mrun = mnew;
      lsum *= al;
#pragma unroll
      for (int db = 0; db < 2; ++db)
#pragma unroll
        for (int r = 0; r < 16; ++r) o[db][r] *= al;
    }

#pragma unroll
    for (int jb = 0; jb < 2; ++jb)
#pragma unroll
      for (int r = 0; r < 16; ++r) s[jb][r] = exp2f(s[jb][r] - mrun);

    f32x16 av = s[0] + s[1];
    float a8[8], a4[4];
#pragma unroll
    for (int i = 0; i < 8; ++i) a8[i] = av[i] + av[i + 8];
#pragma unroll
    for (int i = 0; i < 4; ++i) a4[i] = a8[i] + a8[i + 4];
    float ps = (a4[0] + a4[1]) + (a4[2] + a4[3]);
    ps += __shfl_xor(ps, 32);
    lsum += ps;

    // P^T -> B-operand frags (cvt_pk + permlane32 half-swaps, T12)
    bf16x8 pfrag[4];
#pragma unroll
    for (int jb = 0; jb < 2; ++jb) {
      int pw[8];
#pragma unroll
      for (int g = 0; g < 8; ++g) pw[g] = pk2(s[jb][2 * g], s[jb][2 * g + 1]);
      pl32swap(pw[0], pw[2]);
      pl32swap(pw[1], pw[3]);
      pl32swap(pw[4], pw[6]);
      pl32swap(pw[5], pw[7]);
      i32x4 f0 = {pw[0], pw[1], pw[2], pw[3]};
      i32x4 f1 = {pw[4], pw[5], pw[6], pw[7]};
      pfrag[jb * 2] = __builtin_bit_cast(bf16x8, f0);
      pfrag[jb * 2 + 1] = __builtin_bit_cast(bf16x8, f1);
    }

    // O^T += V^T · P^T
    __builtin_amdgcn_s_setprio(1);
#pragma unroll
    for (int db = 0; db < 2; ++db)
#pragma unroll
      for (int jt = 0; jt < 4; ++jt) {
        bf16x8 vf = *(const bf16x8*)(VsC + voff[db][jt]);
        o[db] = __builtin_amdgcn_mfma_f32_32x32x16_bf16(vf, pfrag[jt], o[db], 0, 0, 0);
      }
    __builtin_amdgcn_s_setprio(0);

    if (pf) writeV(cur ^ 1, vA, vC);
    __syncthreads();
  }

  // epilogue: write un-normalized O^T (bf16) + (m,l); combine kernel normalizes
  bf16_t* op = Opart + (int64_t)c * (Bx * Nx * DIMx) +
               (int64_t)(b * Nx + qrow) * DIMx + h * HDx;
#pragma unroll
  for (int db = 0; db < 2; ++db)
#pragma unroll
    for (int g = 0; g < 4; ++g) {
      bf16x4 ov;
#pragma unroll
      for (int r = 0; r < 4; ++r) ov[r] = (bf16_t)o[db][g * 4 + r];
      *(bf16x4*)(op + db * 32 + g * 8 + hi * 4) = ov;
    }
  if (hi == 0)
    ML[((int64_t)(c * Bx + b) * Hx + h) * Nx + qrow] = make_float2(mrun, lsum);
}

// ---------------- combine: merge the two J-chunks ----------------
__global__ void k_combine(const bf16_t* __restrict__ Op, const float2* __restrict__ ML,
                          bf16_t* __restrict__ Ho) {
  const int64_t CH = (int64_t)Bx * Nx * DIMx;  // 4M elems per chunk
  int i = blockIdx.x * blockDim.x + threadIdx.x;  // one per 8 elems
  const int total = (int)(CH >> 3);
  if (i >= total) return;
  int64_t off = (int64_t)i * 8;
  int bqh = (int)(off >> 6);         // (b*N+q)*16 + h
  int h = bqh & 15;
  int bq = bqh >> 4;
  int b = bq >> 11, q = bq & (Nx - 1);
  float2 ml0 = ML[((int64_t)b * Hx + h) * Nx + q];
  float2 ml1 = ML[((int64_t)(Bx + b) * Hx + h) * Nx + q];
  float M = fmaxf(ml0.x, ml1.x);
  float a0 = exp2f(ml0.x - M), a1 = exp2f(ml1.x - M);
  float inv = 1.f / (a0 * ml0.y + a1 * ml1.y);
  a0 *= inv;
  a1 *= inv;
  bf16x8 v0 = *(const bf16x8*)(Op + off);
  bf16x8 v1 = *(const bf16x8*)(Op + CH + off);
  bf16x8 outv;
#pragma unroll
  for (int r = 0; r < 8; ++r)
    outv[r] = (bf16_t)(a0 * (float)v0[r] + a1 * (float)v1[r]);
  *(bf16x8*)(Ho + off) = outv;
}

// ---------------- launcher ----------------
extern "C" void kernel_launch(void* const* d_in, const int* in_sizes, int n_in,
                              void* d_out, int out_size, void* d_ws, size_t ws_size,
                              hipStream_t stream) {
  const float* x    = (const float*)d_in[0];
  const float* mem  = (const float*)d_in[1];
  const float* expm = (const float*)d_in[2];
  const float* Wq   = (const float*)d_in[3];
  const float* Wkv  = (const float*)d_in[4];
  const float* Wo   = (const float*)d_in[5];
  const float* bo   = (const float*)d_in[6];
  float* out = (float*)d_out;

  bf16_t* p = (bf16_t*)d_ws;
  bf16_t* xb   = p; p += (size_t)Bx * Nx * DIMx;        // dead after Q-GEMM -> ML
  bf16_t* ctxb = p; p += (size_t)Bx * Jx * DIMx;        // dead after KV-GEMM -> Opart
  bf16_t* WqT  = p; p += (size_t)DIMx * DIMx;
  bf16_t* WkvT = p; p += (size_t)DIMx * 2 * DIMx;
  bf16_t* WoT  = p; p += (size_t)DIMx * DIMx;
  bf16_t* Qb   = p; p += (size_t)Bx * Nx * DIMx;
  bf16_t* KVb  = p; p += (size_t)Bx * Jx * 2 * DIMx;
  bf16_t* Ho   = p; p += (size_t)Bx * Nx * DIMx;

  bf16_t* Opart = ctxb;          // 2 x 4M bf16 = 16MB, fits ctxb exactly
  float2* ML    = (float2*)xb;   // 128K float2 = 1MB, fits xb

  k_build_bf16<<<4096, 256, 0, stream>>>(x, mem, xb, ctxb);
  k_transpose_w<<<1024, 256, 0, stream>>>(Wq, WqT, DIMx, DIMx);
  k_transpose_w<<<2048, 256, 0, stream>>>(Wkv, WkvT, DIMx, 2 * DIMx);
  k_transpose_w<<<1024, 256, 0, stream>>>(Wo, WoT, DIMx, DIMx);

  const float qscale = 0.125f * 1.4426950408889634f;  // 1/sqrt(64) * log2(e)
  k_gemm_bt<0><<<dim3(1024 / 128, 4096 / 128), 256, 0, stream>>>(
      xb, WqT, Qb, nullptr, nullptr, 0x7fffffff, qscale, Bx * Nx, DIMx, DIMx);
  k_gemm_bt<0><<<dim3(2048 / 128, 8192 / 128), 256, 0, stream>>>(
      ctxb, WkvT, KVb, nullptr, expm, DIMx, 1.0f, Bx * Jx, 2 * DIMx, DIMx);

  k_attn<<<1024, 256, 0, stream>>>(Qb, KVb, Opart, ML);
  k_combine<<<(Bx * Nx * DIMx / 8 + 255) / 256, 256, 0, stream>>>(Opart, ML, Ho);

  k_gemm_bt<1><<<dim3(1024 / 128, 4096 / 128), 256, 0, stream>>>(
      Ho, WoT, out, bo, nullptr, 0x7fffffff, 1.0f, Bx * Nx, DIMx, DIMx);
}

// Round 8
// 276.048 us; speedup vs baseline: 1.9174x; 1.0906x over previous
//
#include <hip/hip_runtime.h>
#include <cstdint>

typedef __bf16 bf16_t;
typedef __attribute__((ext_vector_type(2))) __bf16 bf16x2;
typedef __attribute__((ext_vector_type(4))) __bf16 bf16x4;
typedef __attribute__((ext_vector_type(8))) __bf16 bf16x8;
typedef __attribute__((ext_vector_type(4))) float f32x4;
typedef __attribute__((ext_vector_type(16))) float f32x16;
typedef __attribute__((ext_vector_type(4))) int i32x4;

constexpr int Bx = 2, Nx = 2048, MEMx = 2048, Jx = 4096, DIMx = 1024, Hx = 16, HDx = 64;

__device__ __forceinline__ void gload_lds16(const bf16_t* g, bf16_t* lds) {
  __builtin_amdgcn_global_load_lds(
      (const __attribute__((address_space(1))) unsigned int*)g,
      (__attribute__((address_space(3))) unsigned int*)lds, 16, 0, 0);
}

__device__ __forceinline__ int pk2(float a, float b) {
  bf16x2 t;
  t[0] = (bf16_t)a;
  t[1] = (bf16_t)b;
  return __builtin_bit_cast(int, t);
}

__device__ __forceinline__ void pl32swap(int& a, int& b) {
  asm volatile("v_permlane32_swap_b32 %0, %1" : "+v"(a), "+v"(b));
}

__device__ __forceinline__ float fmax3(float a, float b, float c) {
  float d;
  asm("v_max3_f32 %0, %1, %2, %3" : "=v"(d) : "v"(a), "v"(b), "v"(c));
  return d;
}

// ---------------- convert / pack kernels ----------------
__global__ void k_build_bf16(const float* __restrict__ x, const float* __restrict__ mem,
                             bf16_t* __restrict__ xb, bf16_t* __restrict__ ctxb) {
  const int XT = Bx * Nx * DIMx;
  const int CT = Bx * Jx * DIMx;
  for (int i = blockIdx.x * blockDim.x + threadIdx.x; i < XT + CT;
       i += gridDim.x * blockDim.x) {
    if (i < XT) {
      xb[i] = (bf16_t)x[i];
    } else {
      int c = i - XT;
      int bb = c / (Jx * DIMx);
      int rr = c % (Jx * DIMx);
      int j = rr / DIMx, d = rr % DIMx;
      float v = (j < MEMx) ? mem[(int64_t)(bb * MEMx + j) * DIMx + d]
                           : x[(int64_t)(bb * Nx + (j - MEMx)) * DIMx + d];
      ctxb[c] = (bf16_t)v;
    }
  }
}

__global__ void k_transpose_w(const float* __restrict__ W, bf16_t* __restrict__ WT,
                              int K, int Nc) {
  int total = K * Nc;
  for (int i = blockIdx.x * blockDim.x + threadIdx.x; i < total;
       i += gridDim.x * blockDim.x) {
    int n = i / K, k = i % K;
    WT[i] = (bf16_t)W[(int64_t)k * Nc + n];
  }
}

// ---------------- GEMM: C[M,Nc] = A[M,K] @ BT[Nc,K]^T (2-phase prefetch) ------
// MODE 0: bf16 out (*scale).  MODE 1: f32 out + bias.
// MODE 2: KV split — cols<1024 -> Kbuf[row][col] bf16; cols>=1024 -> V,
//         gated by gate[row], written TRANSPOSED to VT[(b*16+h)*64+d][j].
template <int MODE>
__launch_bounds__(256)
__global__ void k_gemm_bt(const bf16_t* __restrict__ A, const bf16_t* __restrict__ BT,
                          void* __restrict__ Cv, const float* __restrict__ bias,
                          const float* __restrict__ gate, bf16_t* __restrict__ VT,
                          float scale, int M, int Nc, int K) {
  __shared__ bf16_t As[2][128 * 32];
  __shared__ bf16_t Bs[2][128 * 32];
  const int tid = threadIdx.x;
  const int w = tid >> 6, l = tid & 63;
  const int lr = l & 15, lg = l >> 4;
  const int m0 = blockIdx.y * 128, n0 = blockIdx.x * 128;
  const int wm = (w >> 1) * 64, wn = (w & 1) * 64;

  const int srow = w * 16 + (l >> 2);
  const int scol = (l & 3) * 8;
  const bf16_t* ga0 = A + (int64_t)(m0 + srow) * K + scol;
  const bf16_t* gb0 = BT + (int64_t)(n0 + srow) * K + scol;

  auto stage = [&](int bufi, int k0) {
    bf16_t* lA = &As[bufi][0] + w * 512;
    bf16_t* lB = &Bs[bufi][0] + w * 512;
    gload_lds16(ga0 + k0, lA);
    gload_lds16(ga0 + (int64_t)64 * K + k0, lA + 2048);
    gload_lds16(gb0 + k0, lB);
    gload_lds16(gb0 + (int64_t)64 * K + k0, lB + 2048);
  };

  f32x4 acc[4][4] = {};

  stage(0, 0);
  __syncthreads();

  const int nsteps = K >> 5;
  for (int t = 0; t < nsteps; ++t) {
    const int cur = t & 1;
    if (t + 1 < nsteps) stage(cur ^ 1, (t + 1) << 5);

    bf16x8 af[4], bfr[4];
#pragma unroll
    for (int q = 0; q < 4; ++q)
      af[q] = *(const bf16x8*)(&As[cur][0] + (wm + q * 16 + lr) * 32 + lg * 8);
#pragma unroll
    for (int q = 0; q < 4; ++q)
      bfr[q] = *(const bf16x8*)(&Bs[cur][0] + (wn + q * 16 + lr) * 32 + lg * 8);
#pragma unroll
    for (int mt = 0; mt < 4; ++mt)
#pragma unroll
      for (int nt = 0; nt < 4; ++nt)
        acc[mt][nt] = __builtin_amdgcn_mfma_f32_16x16x32_bf16(af[mt], bfr[nt],
                                                              acc[mt][nt], 0, 0, 0);
    __syncthreads();
  }

#pragma unroll
  for (int mt = 0; mt < 4; ++mt) {
#pragma unroll
    for (int nt = 0; nt < 4; ++nt) {
      int col = n0 + wn + nt * 16 + lr;
      int row0 = m0 + wm + mt * 16 + lg * 4;
      if constexpr (MODE == 0) {
#pragma unroll
        for (int r = 0; r < 4; ++r)
          ((bf16_t*)Cv)[(int64_t)(row0 + r) * Nc + col] =
              (bf16_t)(acc[mt][nt][r] * scale);
      } else if constexpr (MODE == 1) {
#pragma unroll
        for (int r = 0; r < 4; ++r)
          ((float*)Cv)[(int64_t)(row0 + r) * Nc + col] = acc[mt][nt][r] + bias[col];
      } else {
        if (col < 1024) {
#pragma unroll
          for (int r = 0; r < 4; ++r)
            ((bf16_t*)Cv)[(int64_t)(row0 + r) * 1024 + col] = (bf16_t)acc[mt][nt][r];
        } else {
          int hh = (col - 1024) >> 6, dd = col & 63;
          int bb = row0 >> 12, jj = row0 & (Jx - 1);
          bf16x4 ov;
#pragma unroll
          for (int r = 0; r < 4; ++r)
            ov[r] = (bf16_t)(acc[mt][nt][r] * gate[row0 + r]);
          *(bf16x4*)(VT + (((int64_t)(bb * Hx + hh) * HDx + dd) << 12) + jj) = ov;
        }
      }
    }
  }
}

// ---------------- flash attention, J-chunked, counted-vmcnt pipeline ---------
// 1024 blocks: bits[3:0]=qi, [7:4]=h, [8]=chunk, [9]=b. 4 waves x 32 q-rows.
// KV-tile 64, double-buffered; K and V^T both staged by global_load_lds DMA
// (V^T precomputed by the KV GEMM). Depth-2 pipeline: s_waitcnt vmcnt(4) +
// raw s_barrier — never drains to 0 in the loop (T3/T4).
__launch_bounds__(256)
__global__ void k_attn(const bf16_t* __restrict__ Q, const bf16_t* __restrict__ Kbuf,
                       const bf16_t* __restrict__ VT, bf16_t* __restrict__ Opart,
                       float2* __restrict__ ML) {
  __shared__ bf16_t Ks[2][64 * 64];   // byte = j*128 + ((chunk ^ (j&7))*16)
  __shared__ bf16_t Vs[2][64 * 64];   // V^T: byte = d*128 + ((chunk ^ (d&7))*16)

  const int tid = threadIdx.x;
  const int w = tid >> 6, l = tid & 63;
  const int ql = l & 31, hi = l >> 5;

  const int lin = blockIdx.x;
  const int qi0 = lin & 15, h = (lin >> 4) & 15;
  const int c = (lin >> 8) & 1, b = lin >> 9;
  const int qi = b ? (15 - qi0) : qi0;   // causal-depth pairing within CU family
  const int q0 = qi * 128;

  const bf16_t* Qb = Q + ((int64_t)b * Nx) * DIMx + h * HDx;
  const bf16_t* Kb = Kbuf + ((int64_t)b * Jx) * 1024 + h * HDx;
  const bf16_t* Vb = VT + ((int64_t)(b * Hx + h) * HDx << 12);

  const int qrow = q0 + w * 32 + ql;

  bf16x8 qf[4];
#pragma unroll
  for (int dt = 0; dt < 4; ++dt)
    qf[dt] = *(const bf16x8*)(Qb + (int64_t)qrow * DIMx + dt * 16 + hi * 8);
  asm volatile("s_waitcnt vmcnt(0)" ::: "memory");  // qf resident; clean vmcnt

  int koff[2][4], voff[2][4];
#pragma unroll
  for (int jb = 0; jb < 2; ++jb)
#pragma unroll
    for (int dt = 0; dt < 4; ++dt)
      koff[jb][dt] = (jb * 32 + ql) * 128 + (((dt * 2 + hi) * 16) ^ ((ql & 7) * 16));
#pragma unroll
  for (int db = 0; db < 2; ++db)
#pragma unroll
    for (int jt = 0; jt < 4; ++jt)
      voff[db][jt] = (db * 32 + ql) * 128 + (((jt * 2 + hi) * 16) ^ ((ql & 7) * 16));

  f32x16 o[2] = {};
  float mrun = -1e30f, lsum = 0.f;

  const int srow8 = l >> 3;                    // row within 8-row staging group
  const int swcol = ((l & 7) ^ srow8) * 8;     // inverse-swizzled source col
  const int jstart = c * 2048;
  const int jend = c ? ((Jx < q0 + 128 + MEMx) ? Jx : (q0 + 128 + MEMx)) : 2048;
  const int nt_tiles = (jend - jstart) >> 6;   // always >= 2
  const f32x16 z16 = {};

  const bf16_t* ksrc0 = Kb + (int64_t)(w * 16 + srow8) * 1024 + swcol;
  const bf16_t* vsrc0 = Vb + (int64_t)(w * 16 + srow8) * Jx + swcol;

  auto stage = [&](int bufi, int j0) {
    bf16_t* kd = &Ks[bufi][0] + w * 1024;
    const bf16_t* ks = ksrc0 + (int64_t)j0 * 1024;
    gload_lds16(ks, kd);
    gload_lds16(ks + 8 * 1024, kd + 512);
    bf16_t* vd = &Vs[bufi][0] + w * 1024;
    const bf16_t* vs = vsrc0 + j0;
    gload_lds16(vs, vd);
    gload_lds16(vs + 8 * Jx, vd + 512);
  };

  stage(0, jstart);
  stage(1, jstart + 64);

  for (int t = 0; t < nt_tiles; ++t) {
    const int cur = t & 1;
    const int j0 = jstart + (t << 6);
    if (t + 1 < nt_tiles)
      asm volatile("s_waitcnt vmcnt(4)" ::: "memory");
    else
      asm volatile("s_waitcnt vmcnt(0)" ::: "memory");
    __builtin_amdgcn_s_barrier();            // all waves' tile-t DMA landed
    __builtin_amdgcn_sched_barrier(0);

    const char* KsC = (const char*)&Ks[cur][0];
    const char* VsC = (const char*)&Vs[cur][0];

    // S^T = K · Q^T
    f32x16 s[2];
    __builtin_amdgcn_s_setprio(1);
#pragma unroll
    for (int jb = 0; jb < 2; ++jb) {
      f32x16 acc = z16;
#pragma unroll
      for (int dt = 0; dt < 4; ++dt) {
        bf16x8 kf = *(const bf16x8*)(KsC + koff[jb][dt]);
        acc = __builtin_amdgcn_mfma_f32_32x32x16_bf16(kf, qf[dt], acc, 0, 0, 0);
      }
      s[jb] = acc;
    }
    __builtin_amdgcn_s_setprio(0);

    if (j0 + 63 > q0 + MEMx) {   // self-disables for chunk 0
#pragma unroll
      for (int jb = 0; jb < 2; ++jb)
#pragma unroll
        for (int r = 0; r < 16; ++r) {
          int j = j0 + jb * 32 + (r & 3) + (r >> 2) * 8 + hi * 4;
          if (j > qrow + MEMx) s[jb][r] = -1e30f;
        }
    }

    // tile max (v_max3 tree) + 1 shfl
    float t12[12];
#pragma unroll
    for (int i = 0; i < 10; ++i)
      t12[i] = fmax3(s[(3 * i) >> 4][(3 * i) & 15], s[(3 * i + 1) >> 4][(3 * i + 1) & 15],
                     s[(3 * i + 2) >> 4][(3 * i + 2) & 15]);
    t12[10] = s[1][14];
    t12[11] = s[1][15];
    float t4[4];
#pragma unroll
    for (int i = 0; i < 4; ++i) t4[i] = fmax3(t12[3 * i], t12[3 * i + 1], t12[3 * i + 2]);
    float tm = fmaxf(fmax3(t4[0], t4[1], t4[2]), t4[3]);
    tm = fmaxf(tm, __shfl_xor(tm, 32));

    if (!__all(tm <= mrun + 8.f)) {
      float mnew = fmaxf(mrun, tm);
      float al = exp2f(mrun - mnew);
      mrun = mnew;
      lsum *= al;
#pragma unroll
      for (int db = 0; db < 2; ++db)
#pragma unroll
        for (int r = 0; r < 16; ++r) o[db][r] *= al;
    }

#pragma unroll
    for (int jb = 0; jb < 2; ++jb)
#pragma unroll
      for (int r = 0; r < 16; ++r) s[jb][r] = exp2f(s[jb][r] - mrun);

    f32x16 av = s[0] + s[1];
    float a8[8], a4[4];
#pragma unroll
    for (int i = 0; i < 8; ++i) a8[i] = av[i] + av[i + 8];
#pragma unroll
    for (int i = 0; i < 4; ++i) a4[i] = a8[i] + a8[i + 4];
    float ps = (a4[0] + a4[1]) + (a4[2] + a4[3]);
    ps += __shfl_xor(ps, 32);
    lsum += ps;

    // P^T -> B-operand frags (cvt_pk + permlane32 half-swaps, T12)
    bf16x8 pfrag[4];
#pragma unroll
    for (int jb = 0; jb < 2; ++jb) {
      int pw[8];
#pragma unroll
      for (int g = 0; g < 8; ++g) pw[g] = pk2(s[jb][2 * g], s[jb][2 * g + 1]);
      pl32swap(pw[0], pw[2]);
      pl32swap(pw[1], pw[3]);
      pl32swap(pw[4], pw[6]);
      pl32swap(pw[5], pw[7]);
      i32x4 f0 = {pw[0], pw[1], pw[2], pw[3]};
      i32x4 f1 = {pw[4], pw[5], pw[6], pw[7]};
      pfrag[jb * 2] = __builtin_bit_cast(bf16x8, f0);
      pfrag[jb * 2 + 1] = __builtin_bit_cast(bf16x8, f1);
    }

    // O^T += V^T · P^T
    __builtin_amdgcn_s_setprio(1);
#pragma unroll
    for (int db = 0; db < 2; ++db)
#pragma unroll
      for (int jt = 0; jt < 4; ++jt) {
        bf16x8 vf = *(const bf16x8*)(VsC + voff[db][jt]);
        o[db] = __builtin_amdgcn_mfma_f32_32x32x16_bf16(vf, pfrag[jt], o[db], 0, 0, 0);
      }
    __builtin_amdgcn_s_setprio(0);

    __builtin_amdgcn_s_barrier();            // all waves done reading buf[cur]
    __builtin_amdgcn_sched_barrier(0);
    if (t + 2 < nt_tiles) stage(cur, jstart + ((t + 2) << 6));
  }

  // epilogue: write un-normalized O^T (bf16) + (m,l); k_combine normalizes
  bf16_t* op = Opart + (int64_t)c * (Bx * Nx * DIMx) +
               (int64_t)(b * Nx + qrow) * DIMx + h * HDx;
#pragma unroll
  for (int db = 0; db < 2; ++db)
#pragma unroll
    for (int g = 0; g < 4; ++g) {
      bf16x4 ov;
#pragma unroll
      for (int r = 0; r < 4; ++r) ov[r] = (bf16_t)o[db][g * 4 + r];
      *(bf16x4*)(op + db * 32 + g * 8 + hi * 4) = ov;
    }
  if (hi == 0)
    ML[((int64_t)(c * Bx + b) * Hx + h) * Nx + qrow] = make_float2(mrun, lsum);
}

// ---------------- combine: merge the two J-chunks ----------------
__global__ void k_combine(const bf16_t* __restrict__ Op, const float2* __restrict__ ML,
                          bf16_t* __restrict__ Ho) {
  const int64_t CH = (int64_t)Bx * Nx * DIMx;
  int i = blockIdx.x * blockDim.x + threadIdx.x;
  const int total = (int)(CH >> 3);
  if (i >= total) return;
  int64_t off = (int64_t)i * 8;
  int bqh = (int)(off >> 6);
  int h = bqh & 15;
  int bq = bqh >> 4;
  int b = bq >> 11, q = bq & (Nx - 1);
  float2 ml0 = ML[((int64_t)b * Hx + h) * Nx + q];
  float2 ml1 = ML[((int64_t)(Bx + b) * Hx + h) * Nx + q];
  float M = fmaxf(ml0.x, ml1.x);
  float a0 = exp2f(ml0.x - M), a1 = exp2f(ml1.x - M);
  float inv = 1.f / (a0 * ml0.y + a1 * ml1.y);
  a0 *= inv;
  a1 *= inv;
  bf16x8 v0 = *(const bf16x8*)(Op + off);
  bf16x8 v1 = *(const bf16x8*)(Op + CH + off);
  bf16x8 outv;
#pragma unroll
  for (int r = 0; r < 8; ++r)
    outv[r] = (bf16_t)(a0 * (float)v0[r] + a1 * (float)v1[r]);
  *(bf16x8*)(Ho + off) = outv;
}

// ---------------- launcher ----------------
extern "C" void kernel_launch(void* const* d_in, const int* in_sizes, int n_in,
                              void* d_out, int out_size, void* d_ws, size_t ws_size,
                              hipStream_t stream) {
  const float* x    = (const float*)d_in[0];
  const float* mem  = (const float*)d_in[1];
  const float* expm = (const float*)d_in[2];
  const float* Wq   = (const float*)d_in[3];
  const float* Wkv  = (const float*)d_in[4];
  const float* Wo   = (const float*)d_in[5];
  const float* bo   = (const float*)d_in[6];
  float* out = (float*)d_out;

  bf16_t* p = (bf16_t*)d_ws;
  bf16_t* xb   = p; p += (size_t)Bx * Nx * DIMx;        // dead after Q-GEMM -> ML
  bf16_t* ctxb = p; p += (size_t)Bx * Jx * DIMx;        // dead after KV-GEMM -> Opart
  bf16_t* WqT  = p; p += (size_t)DIMx * DIMx;
  bf16_t* WkvT = p; p += (size_t)DIMx * 2 * DIMx;
  bf16_t* WoT  = p; p += (size_t)DIMx * DIMx;
  bf16_t* Qb   = p; p += (size_t)Bx * Nx * DIMx;
  bf16_t* KVb  = p; p += (size_t)Bx * Jx * 2 * DIMx;    // split: K half + VT half
  bf16_t* Ho   = p; p += (size_t)Bx * Nx * DIMx;

  bf16_t* Kbuf = KVb;                              // [B*J][1024]
  bf16_t* VT   = KVb + (size_t)Bx * Jx * 1024;     // [(b*16+h)*64+d][J]
  bf16_t* Opart = ctxb;                            // 2 x 4M bf16 = 16MB
  float2* ML    = (float2*)xb;                     // 128K float2 = 1MB

  k_build_bf16<<<4096, 256, 0, stream>>>(x, mem, xb, ctxb);
  k_transpose_w<<<1024, 256, 0, stream>>>(Wq, WqT, DIMx, DIMx);
  k_transpose_w<<<2048, 256, 0, stream>>>(Wkv, WkvT, DIMx, 2 * DIMx);
  k_transpose_w<<<1024, 256, 0, stream>>>(Wo, WoT, DIMx, DIMx);

  const float qscale = 0.125f * 1.4426950408889634f;  // 1/sqrt(64) * log2(e)
  k_gemm_bt<0><<<dim3(1024 / 128, 4096 / 128), 256, 0, stream>>>(
      xb, WqT, Qb, nullptr, nullptr, nullptr, qscale, Bx * Nx, DIMx, DIMx);
  k_gemm_bt<2><<<dim3(2048 / 128, 8192 / 128), 256, 0, stream>>>(
      ctxb, WkvT, Kbuf, nullptr, expm, VT, 1.0f, Bx * Jx, 2 * DIMx, DIMx);

  k_attn<<<1024, 256, 0, stream>>>(Qb, Kbuf, VT, Opart, ML);
  k_combine<<<(Bx * Nx * DIMx / 8 + 255) / 256, 256, 0, stream>>>(Opart, ML, Ho);

  k_gemm_bt<1><<<dim3(1024 / 128, 4096 / 128), 256, 0, stream>>>(
      Ho, WoT, out, bo, nullptr, nullptr, 1.0f, Bx * Nx, DIMx, DIMx);
}

// Round 9
// 270.744 us; speedup vs baseline: 1.9550x; 1.0196x over previous
//
#include <hip/hip_runtime.h>
#include <cstdint>

typedef __bf16 bf16_t;
typedef __attribute__((ext_vector_type(2))) __bf16 bf16x2;
typedef __attribute__((ext_vector_type(4))) __bf16 bf16x4;
typedef __attribute__((ext_vector_type(8))) __bf16 bf16x8;
typedef __attribute__((ext_vector_type(4))) float f32x4;
typedef __attribute__((ext_vector_type(16))) float f32x16;
typedef __attribute__((ext_vector_type(4))) int i32x4;

constexpr int Bx = 2, Nx = 2048, MEMx = 2048, Jx = 4096, DIMx = 1024, Hx = 16, HDx = 64;

__device__ __forceinline__ void gload_lds16(const bf16_t* g, bf16_t* lds) {
  __builtin_amdgcn_global_load_lds(
      (const __attribute__((address_space(1))) unsigned int*)g,
      (__attribute__((address_space(3))) unsigned int*)lds, 16, 0, 0);
}

__device__ __forceinline__ int pk2(float a, float b) {
  bf16x2 t;
  t[0] = (bf16_t)a;
  t[1] = (bf16_t)b;
  return __builtin_bit_cast(int, t);
}

__device__ __forceinline__ void pl32swap(int& a, int& b) {
  asm volatile("v_permlane32_swap_b32 %0, %1" : "+v"(a), "+v"(b));
}

__device__ __forceinline__ float fmax3(float a, float b, float c) {
  float d;
  asm("v_max3_f32 %0, %1, %2, %3" : "=v"(d) : "v"(a), "v"(b), "v"(c));
  return d;
}

// ---------------- convert / pack kernels ----------------
__global__ void k_build_bf16(const float* __restrict__ x, const float* __restrict__ mem,
                             bf16_t* __restrict__ xb, bf16_t* __restrict__ ctxb) {
  const int XT = Bx * Nx * DIMx;
  const int CT = Bx * Jx * DIMx;
  for (int i = blockIdx.x * blockDim.x + threadIdx.x; i < XT + CT;
       i += gridDim.x * blockDim.x) {
    if (i < XT) {
      xb[i] = (bf16_t)x[i];
    } else {
      int c = i - XT;
      int bb = c / (Jx * DIMx);
      int rr = c % (Jx * DIMx);
      int j = rr / DIMx, d = rr % DIMx;
      float v = (j < MEMx) ? mem[(int64_t)(bb * MEMx + j) * DIMx + d]
                           : x[(int64_t)(bb * Nx + (j - MEMx)) * DIMx + d];
      ctxb[c] = (bf16_t)v;
    }
  }
}

__global__ void k_transpose_w(const float* __restrict__ W, bf16_t* __restrict__ WT,
                              int K, int Nc) {
  int total = K * Nc;
  for (int i = blockIdx.x * blockDim.x + threadIdx.x; i < total;
       i += gridDim.x * blockDim.x) {
    int n = i / K, k = i % K;
    WT[i] = (bf16_t)W[(int64_t)k * Nc + n];
  }
}

// ---------------- GEMM: C[M,Nc] = A[M,K] @ BT[Nc,K]^T ----------------
// Depth-2 counted-vmcnt pipeline (T3/T4): never drain vmcnt to 0 in the loop.
// MODE 0: bf16 out (*scale).  MODE 1: f32 out + bias.
// MODE 2: KV split — cols<1024 -> Kbuf; cols>=1024 -> V gated by gate[row],
//         written TRANSPOSED to VT[(b*16+h)*64+d][j].
template <int MODE>
__launch_bounds__(256)
__global__ void k_gemm_bt(const bf16_t* __restrict__ A, const bf16_t* __restrict__ BT,
                          void* __restrict__ Cv, const float* __restrict__ bias,
                          const float* __restrict__ gate, bf16_t* __restrict__ VT,
                          float scale, int M, int Nc, int K) {
  __shared__ bf16_t As[2][128 * 32];
  __shared__ bf16_t Bs[2][128 * 32];
  const int tid = threadIdx.x;
  const int w = tid >> 6, l = tid & 63;
  const int lr = l & 15, lg = l >> 4;
  const int m0 = blockIdx.y * 128, n0 = blockIdx.x * 128;
  const int wm = (w >> 1) * 64, wn = (w & 1) * 64;

  const int srow = w * 16 + (l >> 2);
  const int scol = (l & 3) * 8;
  const bf16_t* ga0 = A + (int64_t)(m0 + srow) * K + scol;
  const bf16_t* gb0 = BT + (int64_t)(n0 + srow) * K + scol;

  auto stage = [&](int bufi, int k0) {
    bf16_t* lA = &As[bufi][0] + w * 512;
    bf16_t* lB = &Bs[bufi][0] + w * 512;
    gload_lds16(ga0 + k0, lA);
    gload_lds16(ga0 + (int64_t)64 * K + k0, lA + 2048);
    gload_lds16(gb0 + k0, lB);
    gload_lds16(gb0 + (int64_t)64 * K + k0, lB + 2048);
  };

  f32x4 acc[4][4] = {};

  const int nsteps = K >> 5;
  stage(0, 0);
  stage(1, 32);

  for (int t = 0; t < nsteps; ++t) {
    const int cur = t & 1;
    if (t + 1 < nsteps)
      asm volatile("s_waitcnt vmcnt(4)" ::: "memory");
    else
      asm volatile("s_waitcnt vmcnt(0)" ::: "memory");
    __builtin_amdgcn_s_barrier();            // tile t landed for all waves
    __builtin_amdgcn_sched_barrier(0);

    bf16x8 af[4], bfr[4];
#pragma unroll
    for (int q = 0; q < 4; ++q)
      af[q] = *(const bf16x8*)(&As[cur][0] + (wm + q * 16 + lr) * 32 + lg * 8);
#pragma unroll
    for (int q = 0; q < 4; ++q)
      bfr[q] = *(const bf16x8*)(&Bs[cur][0] + (wn + q * 16 + lr) * 32 + lg * 8);
#pragma unroll
    for (int mt = 0; mt < 4; ++mt)
#pragma unroll
      for (int nt = 0; nt < 4; ++nt)
        acc[mt][nt] = __builtin_amdgcn_mfma_f32_16x16x32_bf16(af[mt], bfr[nt],
                                                              acc[mt][nt], 0, 0, 0);
    __builtin_amdgcn_s_barrier();            // all waves done reading buf[cur]
    __builtin_amdgcn_sched_barrier(0);
    if (t + 2 < nsteps) stage(cur, (t + 2) << 5);
  }

#pragma unroll
  for (int mt = 0; mt < 4; ++mt) {
#pragma unroll
    for (int nt = 0; nt < 4; ++nt) {
      int col = n0 + wn + nt * 16 + lr;
      int row0 = m0 + wm + mt * 16 + lg * 4;
      if constexpr (MODE == 0) {
#pragma unroll
        for (int r = 0; r < 4; ++r)
          ((bf16_t*)Cv)[(int64_t)(row0 + r) * Nc + col] =
              (bf16_t)(acc[mt][nt][r] * scale);
      } else if constexpr (MODE == 1) {
#pragma unroll
        for (int r = 0; r < 4; ++r)
          ((float*)Cv)[(int64_t)(row0 + r) * Nc + col] = acc[mt][nt][r] + bias[col];
      } else {
        if (col < 1024) {
#pragma unroll
          for (int r = 0; r < 4; ++r)
            ((bf16_t*)Cv)[(int64_t)(row0 + r) * 1024 + col] = (bf16_t)acc[mt][nt][r];
        } else {
          int hh = (col - 1024) >> 6, dd = col & 63;
          int bb = row0 >> 12, jj = row0 & (Jx - 1);
          bf16x4 ov;
#pragma unroll
          for (int r = 0; r < 4; ++r)
            ov[r] = (bf16_t)(acc[mt][nt][r] * gate[row0 + r]);
          *(bf16x4*)(VT + (((int64_t)(bb * Hx + hh) * HDx + dd) << 12) + jj) = ov;
        }
      }
    }
  }
}

// ---------------- flash attention, J-chunked, counted-vmcnt pipeline ---------
// 1024 blocks: bits[3:0]=qi, [7:4]=h, [8]=chunk, [9]=b. 4 waves x 32 q-rows.
// l computed on the MATRIX pipe: ol = mfma(ones, P) — no VALU sum tree.
__launch_bounds__(256)
__global__ void k_attn(const bf16_t* __restrict__ Q, const bf16_t* __restrict__ Kbuf,
                       const bf16_t* __restrict__ VT, bf16_t* __restrict__ Opart,
                       float2* __restrict__ ML) {
  __shared__ bf16_t Ks[2][64 * 64];   // byte = j*128 + ((chunk ^ (j&7))*16)
  __shared__ bf16_t Vs[2][64 * 64];   // V^T: byte = d*128 + ((chunk ^ (d&7))*16)

  const int tid = threadIdx.x;
  const int w = tid >> 6, l = tid & 63;
  const int ql = l & 31, hi = l >> 5;

  const int lin = blockIdx.x;
  const int qi0 = lin & 15, h = (lin >> 4) & 15;
  const int c = (lin >> 8) & 1, b = lin >> 9;
  const int qi = b ? (15 - qi0) : qi0;   // causal-depth pairing within CU family
  const int q0 = qi * 128;

  const bf16_t* Qb = Q + ((int64_t)b * Nx) * DIMx + h * HDx;
  const bf16_t* Kb = Kbuf + ((int64_t)b * Jx) * 1024 + h * HDx;
  const bf16_t* Vb = VT + ((int64_t)(b * Hx + h) * HDx << 12);

  const int qrow = q0 + w * 32 + ql;

  bf16x8 qf[4];
#pragma unroll
  for (int dt = 0; dt < 4; ++dt)
    qf[dt] = *(const bf16x8*)(Qb + (int64_t)qrow * DIMx + dt * 16 + hi * 8);
  asm volatile("s_waitcnt vmcnt(0)" ::: "memory");  // qf resident; clean vmcnt

  int koff[2][4], voff[2][4];
#pragma unroll
  for (int jb = 0; jb < 2; ++jb)
#pragma unroll
    for (int dt = 0; dt < 4; ++dt)
      koff[jb][dt] = (jb * 32 + ql) * 128 + (((dt * 2 + hi) * 16) ^ ((ql & 7) * 16));
#pragma unroll
  for (int db = 0; db < 2; ++db)
#pragma unroll
    for (int jt = 0; jt < 4; ++jt)
      voff[db][jt] = (db * 32 + ql) * 128 + (((jt * 2 + hi) * 16) ^ ((ql & 7) * 16));

  bf16x8 onesv;
#pragma unroll
  for (int i = 0; i < 8; ++i) onesv[i] = (bf16_t)1.0f;

  f32x16 o[2] = {};
  f32x16 ol = {};                 // l accumulator (all 16 regs identical)
  float mrun = 8.0f;              // safe init: defer-max means no first rescale

  const int srow8 = l >> 3;
  const int swcol = ((l & 7) ^ srow8) * 8;
  const int jstart = c * 2048;
  const int jend = c ? ((Jx < q0 + 128 + MEMx) ? Jx : (q0 + 128 + MEMx)) : 2048;
  const int nt_tiles = (jend - jstart) >> 6;   // always >= 2
  const f32x16 z16 = {};

  const bf16_t* ksrc0 = Kb + (int64_t)(w * 16 + srow8) * 1024 + swcol;
  const bf16_t* vsrc0 = Vb + (int64_t)(w * 16 + srow8) * Jx + swcol;

  auto stage = [&](int bufi, int j0) {
    bf16_t* kd = &Ks[bufi][0] + w * 1024;
    const bf16_t* ks = ksrc0 + (int64_t)j0 * 1024;
    gload_lds16(ks, kd);
    gload_lds16(ks + 8 * 1024, kd + 512);
    bf16_t* vd = &Vs[bufi][0] + w * 1024;
    const bf16_t* vs = vsrc0 + j0;
    gload_lds16(vs, vd);
    gload_lds16(vs + 8 * Jx, vd + 512);
  };

  stage(0, jstart);
  stage(1, jstart + 64);

  for (int t = 0; t < nt_tiles; ++t) {
    const int cur = t & 1;
    const int j0 = jstart + (t << 6);
    if (t + 1 < nt_tiles)
      asm volatile("s_waitcnt vmcnt(4)" ::: "memory");
    else
      asm volatile("s_waitcnt vmcnt(0)" ::: "memory");
    __builtin_amdgcn_s_barrier();
    __builtin_amdgcn_sched_barrier(0);

    const char* KsC = (const char*)&Ks[cur][0];
    const char* VsC = (const char*)&Vs[cur][0];

    // S^T = K · Q^T
    f32x16 s[2];
    __builtin_amdgcn_s_setprio(1);
#pragma unroll
    for (int jb = 0; jb < 2; ++jb) {
      f32x16 acc = z16;
#pragma unroll
      for (int dt = 0; dt < 4; ++dt) {
        bf16x8 kf = *(const bf16x8*)(KsC + koff[jb][dt]);
        acc = __builtin_amdgcn_mfma_f32_32x32x16_bf16(kf, qf[dt], acc, 0, 0, 0);
      }
      s[jb] = acc;
    }
    __builtin_amdgcn_s_setprio(0);

    if (j0 + 63 > q0 + MEMx) {   // self-disables for chunk 0
#pragma unroll
      for (int jb = 0; jb < 2; ++jb)
#pragma unroll
        for (int r = 0; r < 16; ++r) {
          int j = j0 + jb * 32 + (r & 3) + (r >> 2) * 8 + hi * 4;
          if (j > qrow + MEMx) s[jb][r] = -1e30f;
        }
    }

    // tile max (v_max3 tree) + 1 shfl; rescale only if max grew past THR
    float t12[12];
#pragma unroll
    for (int i = 0; i < 10; ++i)
      t12[i] = fmax3(s[(3 * i) >> 4][(3 * i) & 15], s[(3 * i + 1) >> 4][(3 * i + 1) & 15],
                     s[(3 * i + 2) >> 4][(3 * i + 2) & 15]);
    t12[10] = s[1][14];
    t12[11] = s[1][15];
    float t4[4];
#pragma unroll
    for (int i = 0; i < 4; ++i) t4[i] = fmax3(t12[3 * i], t12[3 * i + 1], t12[3 * i + 2]);
    float tm = fmaxf(fmax3(t4[0], t4[1], t4[2]), t4[3]);
    tm = fmaxf(tm, __shfl_xor(tm, 32));

    if (!__all(tm <= mrun + 8.f)) {
      float mnew = fmaxf(mrun, tm);
      float al = exp2f(mrun - mnew);
      mrun = mnew;
#pragma unroll
      for (int r = 0; r < 16; ++r) ol[r] *= al;
#pragma unroll
      for (int db = 0; db < 2; ++db)
#pragma unroll
        for (int r = 0; r < 16; ++r) o[db][r] *= al;
    }

#pragma unroll
    for (int jb = 0; jb < 2; ++jb)
#pragma unroll
      for (int r = 0; r < 16; ++r) s[jb][r] = exp2f(s[jb][r] - mrun);

    // P^T -> B-operand frags (cvt_pk + permlane32 half-swaps, T12)
    bf16x8 pfrag[4];
#pragma unroll
    for (int jb = 0; jb < 2; ++jb) {
      int pw[8];
#pragma unroll
      for (int g = 0; g < 8; ++g) pw[g] = pk2(s[jb][2 * g], s[jb][2 * g + 1]);
      pl32swap(pw[0], pw[2]);
      pl32swap(pw[1], pw[3]);
      pl32swap(pw[4], pw[6]);
      pl32swap(pw[5], pw[7]);
      i32x4 f0 = {pw[0], pw[1], pw[2], pw[3]};
      i32x4 f1 = {pw[4], pw[5], pw[6], pw[7]};
      pfrag[jb * 2] = __builtin_bit_cast(bf16x8, f0);
      pfrag[jb * 2 + 1] = __builtin_bit_cast(bf16x8, f1);
    }

    // O^T += V^T · P^T ; l += ones · P^T (matrix pipe, replaces VALU sum tree)
    __builtin_amdgcn_s_setprio(1);
#pragma unroll
    for (int jt = 0; jt < 4; ++jt) {
      bf16x8 vf0 = *(const bf16x8*)(VsC + voff[0][jt]);
      o[0] = __builtin_amdgcn_mfma_f32_32x32x16_bf16(vf0, pfrag[jt], o[0], 0, 0, 0);
      bf16x8 vf1 = *(const bf16x8*)(VsC + voff[1][jt]);
      o[1] = __builtin_amdgcn_mfma_f32_32x32x16_bf16(vf1, pfrag[jt], o[1], 0, 0, 0);
      ol = __builtin_amdgcn_mfma_f32_32x32x16_bf16(onesv, pfrag[jt], ol, 0, 0, 0);
    }
    __builtin_amdgcn_s_setprio(0);

    __builtin_amdgcn_s_barrier();
    __builtin_amdgcn_sched_barrier(0);
    if (t + 2 < nt_tiles) stage(cur, jstart + ((t + 2) << 6));
  }

  // epilogue: write un-normalized O^T (bf16) + (m,l); k_combine normalizes
  bf16_t* op = Opart + (int64_t)c * (Bx * Nx * DIMx) +
               (int64_t)(b * Nx + qrow) * DIMx + h * HDx;
#pragma unroll
  for (int db = 0; db < 2; ++db)
#pragma unroll
    for (int g = 0; g < 4; ++g) {
      bf16x4 ov;
#pragma unroll
      for (int r = 0; r < 4; ++r) ov[r] = (bf16_t)o[db][g * 4 + r];
      *(bf16x4*)(op + db * 32 + g * 8 + hi * 4) = ov;
    }
  if (hi == 0)
    ML[((int64_t)(c * Bx + b) * Hx + h) * Nx + qrow] = make_float2(mrun, ol[0]);
}

// ---------------- combine: merge the two J-chunks ----------------
__global__ void k_combine(const bf16_t* __restrict__ Op, const float2* __restrict__ ML,
                          bf16_t* __restrict__ Ho) {
  const int64_t CH = (int64_t)Bx * Nx * DIMx;
  int i = blockIdx.x * blockDim.x + threadIdx.x;
  const int total = (int)(CH >> 3);
  if (i >= total) return;
  int64_t off = (int64_t)i * 8;
  int bqh = (int)(off >> 6);
  int h = bqh & 15;
  int bq = bqh >> 4;
  int b = bq >> 11, q = bq & (Nx - 1);
  float2 ml0 = ML[((int64_t)b * Hx + h) * Nx + q];
  float2 ml1 = ML[((int64_t)(Bx + b) * Hx + h) * Nx + q];
  float M = fmaxf(ml0.x, ml1.x);
  float a0 = exp2f(ml0.x - M), a1 = exp2f(ml1.x - M);
  float inv = 1.f / (a0 * ml0.y + a1 * ml1.y);
  a0 *= inv;
  a1 *= inv;
  bf16x8 v0 = *(const bf16x8*)(Op + off);
  bf16x8 v1 = *(const bf16x8*)(Op + CH + off);
  bf16x8 outv;
#pragma unroll
  for (int r = 0; r < 8; ++r)
    outv[r] = (bf16_t)(a0 * (float)v0[r] + a1 * (float)v1[r]);
  *(bf16x8*)(Ho + off) = outv;
}

// ---------------- launcher ----------------
extern "C" void kernel_launch(void* const* d_in, const int* in_sizes, int n_in,
                              void* d_out, int out_size, void* d_ws, size_t ws_size,
                              hipStream_t stream) {
  const float* x    = (const float*)d_in[0];
  const float* mem  = (const float*)d_in[1];
  const float* expm = (const float*)d_in[2];
  const float* Wq   = (const float*)d_in[3];
  const float* Wkv  = (const float*)d_in[4];
  const float* Wo   = (const float*)d_in[5];
  const float* bo   = (const float*)d_in[6];
  float* out = (float*)d_out;

  bf16_t* p = (bf16_t*)d_ws;
  bf16_t* xb   = p; p += (size_t)Bx * Nx * DIMx;        // dead after Q-GEMM -> ML
  bf16_t* ctxb = p; p += (size_t)Bx * Jx * DIMx;        // dead after KV-GEMM -> Opart
  bf16_t* WqT  = p; p += (size_t)DIMx * DIMx;
  bf16_t* WkvT = p; p += (size_t)DIMx * 2 * DIMx;
  bf16_t* WoT  = p; p += (size_t)DIMx * DIMx;
  bf16_t* Qb   = p; p += (size_t)Bx * Nx * DIMx;
  bf16_t* KVb  = p; p += (size_t)Bx * Jx * 2 * DIMx;    // split: K half + VT half
  bf16_t* Ho   = p; p += (size_t)Bx * Nx * DIMx;

  bf16_t* Kbuf = KVb;                              // [B*J][1024]
  bf16_t* VT   = KVb + (size_t)Bx * Jx * 1024;     // [(b*16+h)*64+d][J]
  bf16_t* Opart = ctxb;                            // 2 x 4M bf16 = 16MB
  float2* ML    = (float2*)xb;                     // 128K float2 = 1MB

  k_build_bf16<<<4096, 256, 0, stream>>>(x, mem, xb, ctxb);
  k_transpose_w<<<1024, 256, 0, stream>>>(Wq, WqT, DIMx, DIMx);
  k_transpose_w<<<2048, 256, 0, stream>>>(Wkv, WkvT, DIMx, 2 * DIMx);
  k_transpose_w<<<1024, 256, 0, stream>>>(Wo, WoT, DIMx, DIMx);

  const float qscale = 0.125f * 1.4426950408889634f;  // 1/sqrt(64) * log2(e)
  k_gemm_bt<0><<<dim3(1024 / 128, 4096 / 128), 256, 0, stream>>>(
      xb, WqT, Qb, nullptr, nullptr, nullptr, qscale, Bx * Nx, DIMx, DIMx);
  k_gemm_bt<2><<<dim3(2048 / 128, 8192 / 128), 256, 0, stream>>>(
      ctxb, WkvT, Kbuf, nullptr, expm, VT, 1.0f, Bx * Jx, 2 * DIMx, DIMx);

  k_attn<<<1024, 256, 0, stream>>>(Qb, Kbuf, VT, Opart, ML);
  k_combine<<<(Bx * Nx * DIMx / 8 + 255) / 256, 256, 0, stream>>>(Opart, ML, Ho);

  k_gemm_bt<1><<<dim3(1024 / 128, 4096 / 128), 256, 0, stream>>>(
      Ho, WoT, out, bo, nullptr, nullptr, 1.0f, Bx * Nx, DIMx, DIMx);
}

// Round 10
// 254.253 us; speedup vs baseline: 2.0818x; 1.0649x over previous
//
#include <hip/hip_runtime.h>
#include <cstdint>

typedef __bf16 bf16_t;
typedef __attribute__((ext_vector_type(2))) __bf16 bf16x2;
typedef __attribute__((ext_vector_type(4))) __bf16 bf16x4;
typedef __attribute__((ext_vector_type(8))) __bf16 bf16x8;
typedef __attribute__((ext_vector_type(4))) float f32x4;
typedef __attribute__((ext_vector_type(16))) float f32x16;
typedef __attribute__((ext_vector_type(4))) int i32x4;

constexpr int Bx = 2, Nx = 2048, MEMx = 2048, Jx = 4096, DIMx = 1024, Hx = 16, HDx = 64;

__device__ __forceinline__ void gload_lds16(const bf16_t* g, bf16_t* lds) {
  __builtin_amdgcn_global_load_lds(
      (const __attribute__((address_space(1))) unsigned int*)g,
      (__attribute__((address_space(3))) unsigned int*)lds, 16, 0, 0);
}

__device__ __forceinline__ int pk2(float a, float b) {
  bf16x2 t;
  t[0] = (bf16_t)a;
  t[1] = (bf16_t)b;
  return __builtin_bit_cast(int, t);
}

__device__ __forceinline__ void pl32swap(int& a, int& b) {
  asm volatile("v_permlane32_swap_b32 %0, %1" : "+v"(a), "+v"(b));
}

__device__ __forceinline__ float fmax3(float a, float b, float c) {
  float d;
  asm("v_max3_f32 %0, %1, %2, %3" : "=v"(d) : "v"(a), "v"(b), "v"(c));
  return d;
}

// ---------------- convert / pack (vectorized, G13) ----------------
// 8 elems/thread: float4 x2 loads, bf16x8 store. All dims are powers of 2.
__global__ void k_build8(const float* __restrict__ x, const float* __restrict__ mem,
                         bf16_t* __restrict__ xb, bf16_t* __restrict__ ctxb) {
  const int XT8 = (Bx * Nx * DIMx) >> 3;   // 512K
  const int CT8 = (Bx * Jx * DIMx) >> 3;   // 1M
  for (int i = blockIdx.x * blockDim.x + threadIdx.x; i < XT8 + CT8;
       i += gridDim.x * blockDim.x) {
    const float* src;
    bf16_t* dst;
    if (i < XT8) {
      src = x + ((int64_t)i << 3);
      dst = xb + ((int64_t)i << 3);
    } else {
      int64_t c = (int64_t)(i - XT8) << 3;
      int bb = (int)(c >> 22);
      int rr = (int)(c & ((1 << 22) - 1));
      int j = rr >> 10, d = rr & 1023;
      src = (j < MEMx) ? mem + (((int64_t)(bb * MEMx + j)) << 10) + d
                       : x + (((int64_t)(bb * Nx + (j - MEMx))) << 10) + d;
      dst = ctxb + c;
    }
    float4 a = *(const float4*)src;
    float4 b = *(const float4*)(src + 4);
    bf16x8 v;
    v[0] = (bf16_t)a.x; v[1] = (bf16_t)a.y; v[2] = (bf16_t)a.z; v[3] = (bf16_t)a.w;
    v[4] = (bf16_t)b.x; v[5] = (bf16_t)b.y; v[6] = (bf16_t)b.z; v[7] = (bf16_t)b.w;
    *(bf16x8*)dst = v;
  }
}

// LDS-tiled transpose: WT[n*K + k] = W[k*Nc + n], coalesced both sides.
__global__ void k_transpose_tiled(const float* __restrict__ W, bf16_t* __restrict__ WT,
                                  int K, int Nc) {
  __shared__ bf16_t t[32][33];
  const int tx = threadIdx.x & 31, ty = threadIdx.x >> 5;  // ty 0..7
  const int n0 = blockIdx.x * 32, k0 = blockIdx.y * 32;
#pragma unroll
  for (int r = 0; r < 4; ++r)
    t[ty + 8 * r][tx] = (bf16_t)W[(int64_t)(k0 + ty + 8 * r) * Nc + n0 + tx];
  __syncthreads();
#pragma unroll
  for (int r = 0; r < 4; ++r)
    WT[(int64_t)(n0 + ty + 8 * r) * K + k0 + tx] = t[tx][ty + 8 * r];
}

// ---------------- GEMM: C[M,Nc] = A[M,K] @ BT[Nc,K]^T ----------------
// Depth-2 counted-vmcnt pipeline. MODE 0: bf16 out (*scale). MODE 1: f32+bias.
// MODE 2: KV split — cols<1024 -> Kbuf; cols>=1024 -> V gated, transposed to VT.
template <int MODE>
__launch_bounds__(256)
__global__ void k_gemm_bt(const bf16_t* __restrict__ A, const bf16_t* __restrict__ BT,
                          void* __restrict__ Cv, const float* __restrict__ bias,
                          const float* __restrict__ gate, bf16_t* __restrict__ VT,
                          float scale, int M, int Nc, int K) {
  __shared__ bf16_t As[2][128 * 32];
  __shared__ bf16_t Bs[2][128 * 32];
  const int tid = threadIdx.x;
  const int w = tid >> 6, l = tid & 63;
  const int lr = l & 15, lg = l >> 4;
  const int m0 = blockIdx.y * 128, n0 = blockIdx.x * 128;
  const int wm = (w >> 1) * 64, wn = (w & 1) * 64;

  const int srow = w * 16 + (l >> 2);
  const int scol = (l & 3) * 8;
  const bf16_t* ga0 = A + (int64_t)(m0 + srow) * K + scol;
  const bf16_t* gb0 = BT + (int64_t)(n0 + srow) * K + scol;

  auto stage = [&](int bufi, int k0) {
    bf16_t* lA = &As[bufi][0] + w * 512;
    bf16_t* lB = &Bs[bufi][0] + w * 512;
    gload_lds16(ga0 + k0, lA);
    gload_lds16(ga0 + (int64_t)64 * K + k0, lA + 2048);
    gload_lds16(gb0 + k0, lB);
    gload_lds16(gb0 + (int64_t)64 * K + k0, lB + 2048);
  };

  f32x4 acc[4][4] = {};

  const int nsteps = K >> 5;
  stage(0, 0);
  stage(1, 32);

  for (int t = 0; t < nsteps; ++t) {
    const int cur = t & 1;
    if (t + 1 < nsteps)
      asm volatile("s_waitcnt vmcnt(4)" ::: "memory");
    else
      asm volatile("s_waitcnt vmcnt(0)" ::: "memory");
    __builtin_amdgcn_s_barrier();
    __builtin_amdgcn_sched_barrier(0);

    bf16x8 af[4], bfr[4];
#pragma unroll
    for (int q = 0; q < 4; ++q)
      af[q] = *(const bf16x8*)(&As[cur][0] + (wm + q * 16 + lr) * 32 + lg * 8);
#pragma unroll
    for (int q = 0; q < 4; ++q)
      bfr[q] = *(const bf16x8*)(&Bs[cur][0] + (wn + q * 16 + lr) * 32 + lg * 8);
#pragma unroll
    for (int mt = 0; mt < 4; ++mt)
#pragma unroll
      for (int nt = 0; nt < 4; ++nt)
        acc[mt][nt] = __builtin_amdgcn_mfma_f32_16x16x32_bf16(af[mt], bfr[nt],
                                                              acc[mt][nt], 0, 0, 0);
    __builtin_amdgcn_s_barrier();
    __builtin_amdgcn_sched_barrier(0);
    if (t + 2 < nsteps) stage(cur, (t + 2) << 5);
  }

#pragma unroll
  for (int mt = 0; mt < 4; ++mt) {
#pragma unroll
    for (int nt = 0; nt < 4; ++nt) {
      int col = n0 + wn + nt * 16 + lr;
      int row0 = m0 + wm + mt * 16 + lg * 4;
      if constexpr (MODE == 0) {
#pragma unroll
        for (int r = 0; r < 4; ++r)
          ((bf16_t*)Cv)[(int64_t)(row0 + r) * Nc + col] =
              (bf16_t)(acc[mt][nt][r] * scale);
      } else if constexpr (MODE == 1) {
#pragma unroll
        for (int r = 0; r < 4; ++r)
          ((float*)Cv)[(int64_t)(row0 + r) * Nc + col] = acc[mt][nt][r] + bias[col];
      } else {
        if (col < 1024) {
#pragma unroll
          for (int r = 0; r < 4; ++r)
            ((bf16_t*)Cv)[(int64_t)(row0 + r) * 1024 + col] = (bf16_t)acc[mt][nt][r];
        } else {
          int hh = (col - 1024) >> 6, dd = col & 63;
          int bb = row0 >> 12, jj = row0 & (Jx - 1);
          bf16x4 ov;
#pragma unroll
          for (int r = 0; r < 4; ++r)
            ov[r] = (bf16_t)(acc[mt][nt][r] * gate[row0 + r]);
          *(bf16x4*)(VT + (((int64_t)(bb * Hx + hh) * HDx + dd) << 12) + jj) = ov;
        }
      }
    }
  }
}

// ---------------- flash attention, equal-split J-chunks ----------------
// 1024 blocks: bits[3:0]=qi, [7:4]=h, [8]=chunk, [9]=b. 4 waves x 32 q-rows.
// Each (b,h,qi) J-range split into two EQUAL halves (balanced block durations).
__launch_bounds__(256)
__global__ void k_attn(const bf16_t* __restrict__ Q, const bf16_t* __restrict__ Kbuf,
                       const bf16_t* __restrict__ VT, bf16_t* __restrict__ Opart,
                       float2* __restrict__ ML) {
  __shared__ bf16_t Ks[2][64 * 64];   // byte = j*128 + ((chunk ^ (j&7))*16)
  __shared__ bf16_t Vs[2][64 * 64];   // V^T: byte = d*128 + ((chunk ^ (d&7))*16)

  const int tid = threadIdx.x;
  const int w = tid >> 6, l = tid & 63;
  const int ql = l & 31, hi = l >> 5;

  const int lin = blockIdx.x;
  const int qi0 = lin & 15, h = (lin >> 4) & 15;
  const int c = (lin >> 8) & 1, b = lin >> 9;
  const int qi = b ? (15 - qi0) : qi0;   // causal-depth pairing within CU family
  const int q0 = qi * 128;

  const bf16_t* Qb = Q + ((int64_t)b * Nx) * DIMx + h * HDx;
  const bf16_t* Kb = Kbuf + ((int64_t)b * Jx) * 1024 + h * HDx;
  const bf16_t* Vb = VT + ((int64_t)(b * Hx + h) * HDx << 12);

  const int qrow = q0 + w * 32 + ql;

  bf16x8 qf[4];
#pragma unroll
  for (int dt = 0; dt < 4; ++dt)
    qf[dt] = *(const bf16x8*)(Qb + (int64_t)qrow * DIMx + dt * 16 + hi * 8);
  asm volatile("s_waitcnt vmcnt(0)" ::: "memory");  // qf resident; clean vmcnt

  int koff[2][4], voff[2][4];
#pragma unroll
  for (int jb = 0; jb < 2; ++jb)
#pragma unroll
    for (int dt = 0; dt < 4; ++dt)
      koff[jb][dt] = (jb * 32 + ql) * 128 + (((dt * 2 + hi) * 16) ^ ((ql & 7) * 16));
#pragma unroll
  for (int db = 0; db < 2; ++db)
#pragma unroll
    for (int jt = 0; jt < 4; ++jt)
      voff[db][jt] = (db * 32 + ql) * 128 + (((jt * 2 + hi) * 16) ^ ((ql & 7) * 16));

  bf16x8 onesv;
#pragma unroll
  for (int i = 0; i < 8; ++i) onesv[i] = (bf16_t)1.0f;

  f32x16 o[2] = {};
  f32x16 ol = {};                 // l accumulator (matrix pipe)
  float mrun = 8.0f;              // defer-max: no first-tile rescale

  const int srow8 = l >> 3;
  const int swcol = ((l & 7) ^ srow8) * 8;
  // equal split: T tiles total, chunk0 = [0, T/2), chunk1 = [T/2, T)
  const int jend_full = (Jx < q0 + 128 + MEMx) ? Jx : (q0 + 128 + MEMx);
  const int T = jend_full >> 6;        // 34..64, always even
  const int half = T >> 1;
  const int jstart = c ? (half << 6) : 0;
  const int nt_tiles = c ? (T - half) : half;   // >= 17
  const f32x16 z16 = {};

  const bf16_t* ksrc0 = Kb + (int64_t)(w * 16 + srow8) * 1024 + swcol;
  const bf16_t* vsrc0 = Vb + (int64_t)(w * 16 + srow8) * Jx + swcol;

  auto stage = [&](int bufi, int j0) {
    bf16_t* kd = &Ks[bufi][0] + w * 1024;
    const bf16_t* ks = ksrc0 + (int64_t)j0 * 1024;
    gload_lds16(ks, kd);
    gload_lds16(ks + 8 * 1024, kd + 512);
    bf16_t* vd = &Vs[bufi][0] + w * 1024;
    const bf16_t* vs = vsrc0 + j0;
    gload_lds16(vs, vd);
    gload_lds16(vs + 8 * Jx, vd + 512);
  };

  stage(0, jstart);
  stage(1, jstart + 64);

  for (int t = 0; t < nt_tiles; ++t) {
    const int cur = t & 1;
    const int j0 = jstart + (t << 6);
    if (t + 1 < nt_tiles)
      asm volatile("s_waitcnt vmcnt(4)" ::: "memory");
    else
      asm volatile("s_waitcnt vmcnt(0)" ::: "memory");
    __builtin_amdgcn_s_barrier();
    __builtin_amdgcn_sched_barrier(0);

    const char* KsC = (const char*)&Ks[cur][0];
    const char* VsC = (const char*)&Vs[cur][0];

    // S^T = K · Q^T
    f32x16 s[2];
    __builtin_amdgcn_s_setprio(1);
#pragma unroll
    for (int jb = 0; jb < 2; ++jb) {
      f32x16 acc = z16;
#pragma unroll
      for (int dt = 0; dt < 4; ++dt) {
        bf16x8 kf = *(const bf16x8*)(KsC + koff[jb][dt]);
        acc = __builtin_amdgcn_mfma_f32_32x32x16_bf16(kf, qf[dt], acc, 0, 0, 0);
      }
      s[jb] = acc;
    }
    __builtin_amdgcn_s_setprio(0);

    if (j0 + 63 > q0 + MEMx) {   // only the last tiles of chunk1
#pragma unroll
      for (int jb = 0; jb < 2; ++jb)
#pragma unroll
        for (int r = 0; r < 16; ++r) {
          int j = j0 + jb * 32 + (r & 3) + (r >> 2) * 8 + hi * 4;
          if (j > qrow + MEMx) s[jb][r] = -1e30f;
        }
    }

    // tile max (v_max3 tree) + 1 shfl; rescale only if max grew past THR
    float t12[12];
#pragma unroll
    for (int i = 0; i < 10; ++i)
      t12[i] = fmax3(s[(3 * i) >> 4][(3 * i) & 15], s[(3 * i + 1) >> 4][(3 * i + 1) & 15],
                     s[(3 * i + 2) >> 4][(3 * i + 2) & 15]);
    t12[10] = s[1][14];
    t12[11] = s[1][15];
    float t4[4];
#pragma unroll
    for (int i = 0; i < 4; ++i) t4[i] = fmax3(t12[3 * i], t12[3 * i + 1], t12[3 * i + 2]);
    float tm = fmaxf(fmax3(t4[0], t4[1], t4[2]), t4[3]);
    tm = fmaxf(tm, __shfl_xor(tm, 32));

    if (!__all(tm <= mrun + 8.f)) {
      float mnew = fmaxf(mrun, tm);
      float al = exp2f(mrun - mnew);
      mrun = mnew;
#pragma unroll
      for (int r = 0; r < 16; ++r) ol[r] *= al;
#pragma unroll
      for (int db = 0; db < 2; ++db)
#pragma unroll
        for (int r = 0; r < 16; ++r) o[db][r] *= al;
    }

#pragma unroll
    for (int jb = 0; jb < 2; ++jb)
#pragma unroll
      for (int r = 0; r < 16; ++r) s[jb][r] = exp2f(s[jb][r] - mrun);

    // P^T -> B-operand frags (cvt_pk + permlane32 half-swaps, T12)
    bf16x8 pfrag[4];
#pragma unroll
    for (int jb = 0; jb < 2; ++jb) {
      int pw[8];
#pragma unroll
      for (int g = 0; g < 8; ++g) pw[g] = pk2(s[jb][2 * g], s[jb][2 * g + 1]);
      pl32swap(pw[0], pw[2]);
      pl32swap(pw[1], pw[3]);
      pl32swap(pw[4], pw[6]);
      pl32swap(pw[5], pw[7]);
      i32x4 f0 = {pw[0], pw[1], pw[2], pw[3]};
      i32x4 f1 = {pw[4], pw[5], pw[6], pw[7]};
      pfrag[jb * 2] = __builtin_bit_cast(bf16x8, f0);
      pfrag[jb * 2 + 1] = __builtin_bit_cast(bf16x8, f1);
    }

    // O^T += V^T · P^T ; l += ones · P^T (matrix pipe)
    __builtin_amdgcn_s_setprio(1);
#pragma unroll
    for (int jt = 0; jt < 4; ++jt) {
      bf16x8 vf0 = *(const bf16x8*)(VsC + voff[0][jt]);
      o[0] = __builtin_amdgcn_mfma_f32_32x32x16_bf16(vf0, pfrag[jt], o[0], 0, 0, 0);
      bf16x8 vf1 = *(const bf16x8*)(VsC + voff[1][jt]);
      o[1] = __builtin_amdgcn_mfma_f32_32x32x16_bf16(vf1, pfrag[jt], o[1], 0, 0, 0);
      ol = __builtin_amdgcn_mfma_f32_32x32x16_bf16(onesv, pfrag[jt], ol, 0, 0, 0);
    }
    __builtin_amdgcn_s_setprio(0);

    __builtin_amdgcn_s_barrier();
    __builtin_amdgcn_sched_barrier(0);
    if (t + 2 < nt_tiles) stage(cur, jstart + ((t + 2) << 6));
  }

  // epilogue: write un-normalized O^T (bf16) + (m,l); k_combine normalizes
  bf16_t* op = Opart + (int64_t)c * (Bx * Nx * DIMx) +
               (int64_t)(b * Nx + qrow) * DIMx + h * HDx;
#pragma unroll
  for (int db = 0; db < 2; ++db)
#pragma unroll
    for (int g = 0; g < 4; ++g) {
      bf16x4 ov;
#pragma unroll
      for (int r = 0; r < 4; ++r) ov[r] = (bf16_t)o[db][g * 4 + r];
      *(bf16x4*)(op + db * 32 + g * 8 + hi * 4) = ov;
    }
  if (hi == 0)
    ML[((int64_t)(c * Bx + b) * Hx + h) * Nx + qrow] = make_float2(mrun, ol[0]);
}

// ---------------- combine: merge the two J-chunks ----------------
__global__ void k_combine(const bf16_t* __restrict__ Op, const float2* __restrict__ ML,
                          bf16_t* __restrict__ Ho) {
  const int64_t CH = (int64_t)Bx * Nx * DIMx;
  int i = blockIdx.x * blockDim.x + threadIdx.x;
  const int total = (int)(CH >> 3);
  if (i >= total) return;
  int64_t off = (int64_t)i * 8;
  int bqh = (int)(off >> 6);
  int h = bqh & 15;
  int bq = bqh >> 4;
  int b = bq >> 11, q = bq & (Nx - 1);
  float2 ml0 = ML[((int64_t)b * Hx + h) * Nx + q];
  float2 ml1 = ML[((int64_t)(Bx + b) * Hx + h) * Nx + q];
  float M = fmaxf(ml0.x, ml1.x);
  float a0 = exp2f(ml0.x - M), a1 = exp2f(ml1.x - M);
  float inv = 1.f / (a0 * ml0.y + a1 * ml1.y);
  a0 *= inv;
  a1 *= inv;
  bf16x8 v0 = *(const bf16x8*)(Op + off);
  bf16x8 v1 = *(const bf16x8*)(Op + CH + off);
  bf16x8 outv;
#pragma unroll
  for (int r = 0; r < 8; ++r)
    outv[r] = (bf16_t)(a0 * (float)v0[r] + a1 * (float)v1[r]);
  *(bf16x8*)(Ho + off) = outv;
}

// ---------------- launcher ----------------
extern "C" void kernel_launch(void* const* d_in, const int* in_sizes, int n_in,
                              void* d_out, int out_size, void* d_ws, size_t ws_size,
                              hipStream_t stream) {
  const float* x    = (const float*)d_in[0];
  const float* mem  = (const float*)d_in[1];
  const float* expm = (const float*)d_in[2];
  const float* Wq   = (const float*)d_in[3];
  const float* Wkv  = (const float*)d_in[4];
  const float* Wo   = (const float*)d_in[5];
  const float* bo   = (const float*)d_in[6];
  float* out = (float*)d_out;

  bf16_t* p = (bf16_t*)d_ws;
  bf16_t* xb   = p; p += (size_t)Bx * Nx * DIMx;        // dead after Q-GEMM -> ML
  bf16_t* ctxb = p; p += (size_t)Bx * Jx * DIMx;        // dead after KV-GEMM -> Opart
  bf16_t* WqT  = p; p += (size_t)DIMx * DIMx;
  bf16_t* WkvT = p; p += (size_t)DIMx * 2 * DIMx;
  bf16_t* WoT  = p; p += (size_t)DIMx * DIMx;
  bf16_t* Qb   = p; p += (size_t)Bx * Nx * DIMx;
  bf16_t* KVb  = p; p += (size_t)Bx * Jx * 2 * DIMx;    // split: K half + VT half
  bf16_t* Ho   = p; p += (size_t)Bx * Nx * DIMx;

  bf16_t* Kbuf = KVb;                              // [B*J][1024]
  bf16_t* VT   = KVb + (size_t)Bx * Jx * 1024;     // [(b*16+h)*64+d][J]
  bf16_t* Opart = ctxb;                            // 2 x 4M bf16 = 16MB
  float2* ML    = (float2*)xb;                     // 128K float2 = 1MB

  k_build8<<<2048, 256, 0, stream>>>(x, mem, xb, ctxb);
  k_transpose_tiled<<<dim3(32, 32), 256, 0, stream>>>(Wq, WqT, DIMx, DIMx);
  k_transpose_tiled<<<dim3(64, 32), 256, 0, stream>>>(Wkv, WkvT, DIMx, 2 * DIMx);
  k_transpose_tiled<<<dim3(32, 32), 256, 0, stream>>>(Wo, WoT, DIMx, DIMx);

  const float qscale = 0.125f * 1.4426950408889634f;  // 1/sqrt(64) * log2(e)
  k_gemm_bt<0><<<dim3(1024 / 128, 4096 / 128), 256, 0, stream>>>(
      xb, WqT, Qb, nullptr, nullptr, nullptr, qscale, Bx * Nx, DIMx, DIMx);
  k_gemm_bt<2><<<dim3(2048 / 128, 8192 / 128), 256, 0, stream>>>(
      ctxb, WkvT, Kbuf, nullptr, expm, VT, 1.0f, Bx * Jx, 2 * DIMx, DIMx);

  k_attn<<<1024, 256, 0, stream>>>(Qb, Kbuf, VT, Opart, ML);
  k_combine<<<(Bx * Nx * DIMx / 8 + 255) / 256, 256, 0, stream>>>(Opart, ML, Ho);

  k_gemm_bt<1><<<dim3(1024 / 128, 4096 / 128), 256, 0, stream>>>(
      Ho, WoT, out, bo, nullptr, nullptr, 1.0f, Bx * Nx, DIMx, DIMx);
}